// Round 1
// baseline (195.085 us; speedup 1.0000x reference)
//
#include <hip/hip_runtime.h>
#include <stdint.h>

typedef float f32x4 __attribute__((ext_vector_type(4)));
typedef _Float16 f16x8 __attribute__((ext_vector_type(8)));
typedef _Float16 f16x4 __attribute__((ext_vector_type(4)));

#define LOG2E 1.44269504088896340736f

// global -> LDS direct copy, 16B per lane, wave-uniform LDS base (guide §5)
__device__ __forceinline__ void gload_lds16(const void* g, void* l) {
    auto gp = reinterpret_cast<const uint32_t __attribute__((address_space(1)))*>(
        reinterpret_cast<uintptr_t>(g));
    auto lp = reinterpret_cast<uint32_t __attribute__((address_space(3)))*>(
        reinterpret_cast<uintptr_t>(l));
    __builtin_amdgcn_global_load_lds(gp, lp, 16, 0, 0);
}

// ---------------- prep: f32->f16 converts, qbias=Wq_b+u, bbox geometry ----------------
__global__ __launch_bounds__(256) void mega_prep(
    const float* __restrict__ bbox, const float* __restrict__ ref_bbox,
    const float* __restrict__ roi_feat, const float* __restrict__ ref_feat,
    const float* __restrict__ Wg_w, const float* __restrict__ Wq_w,
    const float* __restrict__ Wk_w, const float* __restrict__ Wv_w,
    const float* __restrict__ Wq_b, const float* __restrict__ uvec,
    _Float16* __restrict__ roi_h, _Float16* __restrict__ ref_h,
    _Float16* __restrict__ wq_h, _Float16* __restrict__ wk_h,
    _Float16* __restrict__ wv_h, _Float16* __restrict__ wg_h,
    float* __restrict__ qbias, float* __restrict__ roig, float* __restrict__ refg)
{
    int idx = blockIdx.x * 256 + threadIdx.x;
    if (idx < 1442048) {
        const float* src; _Float16* dst; int off;
        if (idx < 131072)       { src = roi_feat; dst = roi_h; off = idx; }
        else if (idx < 655360)  { src = ref_feat; dst = ref_h; off = idx - 131072; }
        else if (idx < 917504)  { src = Wq_w;     dst = wq_h;  off = idx - 655360; }
        else if (idx < 1179648) { src = Wk_w;     dst = wk_h;  off = idx - 917504; }
        else if (idx < 1441792) { src = Wv_w;     dst = wv_h;  off = idx - 1179648; }
        else                    { src = Wg_w;     dst = wg_h;  off = idx - 1441792; }
        f32x4 v = *(const f32x4*)(src + (size_t)off * 4);
        f16x4 o;
        o[0] = (_Float16)v[0]; o[1] = (_Float16)v[1];
        o[2] = (_Float16)v[2]; o[3] = (_Float16)v[3];
        *(f16x4*)(dst + (size_t)off * 4) = o;
    } else if (idx < 1442304) {
        int off = idx - 1442048;
        f32x4 a = *(const f32x4*)(Wq_b + off * 4);
        f32x4 b = *(const f32x4*)(uvec + off * 4);
        f32x4 r = a + b;
        *(f32x4*)(qbias + off * 4) = r;
    } else if (idx < 1442816) {
        int n = idx - 1442304;
        f32x4 bb = *(const f32x4*)(bbox + n * 4);
        float w = bb[2] - bb[0] + 1.0f, h = bb[3] - bb[1] + 1.0f;
        f32x4 o1 = {0.5f*(bb[0]+bb[2]), 0.5f*(bb[1]+bb[3]), 1.0f/w, 1.0f/h};
        f32x4 o2 = {__logf(w), __logf(h), 0.f, 0.f};
        *(f32x4*)(roig + n*8) = o1;
        *(f32x4*)(roig + n*8 + 4) = o2;
    } else if (idx < 1444864) {
        int m = idx - 1442816;
        f32x4 bb = *(const f32x4*)(ref_bbox + m * 4);
        float w = bb[2] - bb[0] + 1.0f, h = bb[3] - bb[1] + 1.0f;
        f32x4 o = {0.5f*(bb[0]+bb[2]), 0.5f*(bb[1]+bb[3]), __logf(w), __logf(h)};
        *(f32x4*)(refg + m*4) = o;
    }
}

// ---------------- batched QKV GEMM: C = A*B^T (+bias)*scale, 128x128 tile ----------------
// b<32: Q = roi@Wq^T, scaled by 0.125*log2e, bias=Wq_b+u  -> Qh [512][1024]
// b<160: K = ref@Wk^T + Wk_b                              -> Kh [2048][1024]
// else : V = ref@Wv'^T (Wv' = Wv flat [1024][1024])       -> Vth [1024][2048] (transposed)
__global__ __launch_bounds__(256) void mega_gemm(
    const _Float16* __restrict__ roi_h, const _Float16* __restrict__ ref_h,
    const _Float16* __restrict__ wq_h, const _Float16* __restrict__ wk_h,
    const _Float16* __restrict__ wv_h, const float* __restrict__ qbias,
    const float* __restrict__ Wk_b,
    _Float16* __restrict__ Qh, _Float16* __restrict__ Kh, _Float16* __restrict__ Vth)
{
    __shared__ _Float16 As[128 * 32];
    __shared__ _Float16 Bs[128 * 32];

    int b = blockIdx.x;
    const _Float16 *A, *B;
    const float* bias;
    _Float16* out;
    int tm, tn, mode; float scale;
    if (b < 32)       { A = roi_h; B = wq_h; bias = qbias;   out = Qh;  tm = b >> 3;         tn = b & 7;       mode = 0; scale = 0.125f * LOG2E; }
    else if (b < 160) { A = ref_h; B = wk_h; bias = Wk_b;    out = Kh;  tm = (b-32) >> 3;    tn = (b-32) & 7;  mode = 0; scale = 1.f; }
    else              { A = ref_h; B = wv_h; bias = nullptr; out = Vth; tm = (b-160) >> 3;   tn = (b-160) & 7; mode = 1; scale = 1.f; }

    int tid = threadIdx.x;
    int w = tid >> 6, l = tid & 63, q = l >> 4, t = l & 15;
    int wm = w >> 1, wn = w & 1;
    int m0 = tm * 128, n0 = tn * 128;

    const _Float16* gA  = A + (size_t)(m0 + w*16 + (l >> 2)) * 1024 + (l & 3) * 8;
    const _Float16* gA2 = gA + 64 * 1024;
    const _Float16* gB  = B + (size_t)(n0 + w*16 + (l >> 2)) * 1024 + (l & 3) * 8;
    const _Float16* gB2 = gB + 64 * 1024;
    _Float16* lA  = &As[(w*16) * 32];
    _Float16* lA2 = &As[(64 + w*16) * 32];
    _Float16* lB  = &Bs[(w*16) * 32];
    _Float16* lB2 = &Bs[(64 + w*16) * 32];

    f32x4 acc[4][4];
    #pragma unroll
    for (int i = 0; i < 4; ++i)
        #pragma unroll
        for (int j = 0; j < 4; ++j)
            acc[i][j] = (f32x4){0.f, 0.f, 0.f, 0.f};

    for (int k0 = 0; k0 < 1024; k0 += 32) {
        gload_lds16(gA + k0, lA);
        gload_lds16(gA2 + k0, lA2);
        gload_lds16(gB + k0, lB);
        gload_lds16(gB2 + k0, lB2);
        __syncthreads();
        f16x8 af[4], bfv[4];
        #pragma unroll
        for (int i = 0; i < 4; ++i) {
            af[i]  = *(const f16x8*)&As[(wm*64 + i*16 + t) * 32 + q*8];
            bfv[i] = *(const f16x8*)&Bs[(wn*64 + i*16 + t) * 32 + q*8];
        }
        #pragma unroll
        for (int mi = 0; mi < 4; ++mi)
            #pragma unroll
            for (int ni = 0; ni < 4; ++ni)
                acc[mi][ni] = __builtin_amdgcn_mfma_f32_16x16x32_f16(af[mi], bfv[ni], acc[mi][ni], 0, 0, 0);
        __syncthreads();
    }

    #pragma unroll
    for (int mi = 0; mi < 4; ++mi) {
        #pragma unroll
        for (int ni = 0; ni < 4; ++ni) {
            int col  = n0 + wn*64 + ni*16 + t;
            int row0 = m0 + wm*64 + mi*16 + q*4;
            f32x4 a = acc[mi][ni];
            if (mode == 0) {
                float bb = bias[col];
                #pragma unroll
                for (int r = 0; r < 4; ++r)
                    out[(size_t)(row0 + r) * 1024 + col] = (_Float16)((a[r] + bb) * scale);
            } else {
                f16x4 pk;
                pk[0] = (_Float16)a[0]; pk[1] = (_Float16)a[1];
                pk[2] = (_Float16)a[2]; pk[3] = (_Float16)a[3];
                *(f16x4*)(out + (size_t)col * 2048 + row0) = pk;
            }
        }
    }
}

// ---------------- position prior: relu(Wg @ emb + Wg_b), via MFMA ----------------
// wave handles (n, chunk of 16 m). Lane (q,p): pair p, B-frag e = ks*32+8q+j
// -> component c = 2*ks + (q>>1), sin (q even) / cos (q odd), freq j.
// output prior[n][g][m] f16, layout [(n*16+g)*2048 + m].
__global__ __launch_bounds__(256) void mega_prior(
    const _Float16* __restrict__ wg_h, const float* __restrict__ Wg_b,
    const float* __restrict__ roig, const float* __restrict__ refg,
    _Float16* __restrict__ prior)
{
    int tid = threadIdx.x;
    int w = tid >> 6, l = tid & 63, q = l >> 4, p = l & 15;
    int n = blockIdx.x >> 1, half = blockIdx.x & 1;

    f16x8 wa0 = *(const f16x8*)(wg_h + p*64 + q*8);
    f16x8 wa1 = *(const f16x8*)(wg_h + p*64 + 32 + q*8);
    f32x4 wb = *(const f32x4*)(Wg_b + q*4);

    f32x4 rg1 = *(const f32x4*)(roig + n*8);
    f32x4 rg2 = *(const f32x4*)(roig + n*8 + 4);

    float cf[8];
    #pragma unroll
    for (int f = 0; f < 8; ++f)
        cf[f] = 15.9154943091895336f * __builtin_exp2f(-1.24572303558276059f * (float)f);

    float coff = (q & 1) ? 0.25f : 0.0f;   // cos(x) = sin(x + 1/4 rev)
    bool isX = (q < 2);

    int mstart = half * 1024 + w * 256;
    for (int it = 0; it < 16; ++it) {
        int m = mstart + it * 16 + p;
        f32x4 rg = *(const f32x4*)(refg + m * 4);
        float posA = isX ? __logf(fabsf(rg1[0] - rg[0]) * rg1[2] + 1e-3f)
                         : __logf(fabsf(rg1[1] - rg[1]) * rg1[3] + 1e-3f);
        float posB = isX ? (rg2[0] - rg[2]) : (rg2[1] - rg[3]);
        f16x8 e0, e1;
        #pragma unroll
        for (int f = 0; f < 8; ++f) {
            float a0 = posA * cf[f] + coff; a0 -= floorf(a0);
            float a1 = posB * cf[f] + coff; a1 -= floorf(a1);
            e0[f] = (_Float16)__builtin_amdgcn_sinf(a0);
            e1[f] = (_Float16)__builtin_amdgcn_sinf(a1);
        }
        f32x4 acc = wb;
        acc = __builtin_amdgcn_mfma_f32_16x16x32_f16(wa0, e0, acc, 0, 0, 0);
        acc = __builtin_amdgcn_mfma_f32_16x16x32_f16(wa1, e1, acc, 0, 0, 0);
        _Float16* pp = prior + (size_t)(n * 16) * 2048 + m;
        #pragma unroll
        for (int r = 0; r < 4; ++r)
            pp[(size_t)(q*4 + r) * 2048] = (_Float16)fmaxf(acc[r], 0.f);
    }
}

// ---------------- flash attention, per-wave unit = (g, 16 n-rows, m-quarter) ----------------
// S' = mfma(K, Q_scaled) + log2(prior+1e-6): lane(q,t) owns n=t, m=mb+mi*16+4q+r.
// PV: O^T = mfma_16x16x16(V^T, P^T) — P regs feed B-frag directly.
__global__ __launch_bounds__(256) void mega_attn(
    const _Float16* __restrict__ Qh, const _Float16* __restrict__ Kh,
    const _Float16* __restrict__ Vth, const _Float16* __restrict__ prior,
    float* __restrict__ Opart, float* __restrict__ Mpart, float* __restrict__ Lpart)
{
    int u = blockIdx.x * 4 + (threadIdx.x >> 6);
    int l = threadIdx.x & 63, q = l >> 4, t = l & 15;
    int g = u >> 7, nt = (u >> 2) & 31, s = u & 3;
    int n = nt * 16 + t;

    const _Float16* Qrow = Qh + (size_t)n * 1024 + g * 64;
    f16x8 qf0 = *(const f16x8*)(Qrow + q * 8);
    f16x8 qf1 = *(const f16x8*)(Qrow + 32 + q * 8);

    const _Float16* Pb = prior + (size_t)(n * 16 + g) * 2048;
    const _Float16* Vg = Vth + (size_t)(g * 64) * 2048;

    float mrow = -INFINITY, lsum = 0.f;
    f32x4 O0 = {0,0,0,0}, O1 = {0,0,0,0}, O2 = {0,0,0,0}, O3 = {0,0,0,0};

    for (int c = 0; c < 8; ++c) {
        int mb = s * 512 + c * 64;
        f32x4 sv[4];
        #pragma unroll
        for (int mi = 0; mi < 4; ++mi) {
            f16x4 pr = *(const f16x4*)(Pb + mb + mi * 16 + q * 4);
            f32x4 ci;
            #pragma unroll
            for (int r = 0; r < 4; ++r)
                ci[r] = __log2f((float)pr[r] + 1e-6f);
            const _Float16* Krow = Kh + (size_t)(mb + mi * 16 + t) * 1024 + g * 64;
            f16x8 k0 = *(const f16x8*)(Krow + q * 8);
            f16x8 k1 = *(const f16x8*)(Krow + 32 + q * 8);
            ci = __builtin_amdgcn_mfma_f32_16x16x32_f16(k0, qf0, ci, 0, 0, 0);
            ci = __builtin_amdgcn_mfma_f32_16x16x32_f16(k1, qf1, ci, 0, 0, 0);
            sv[mi] = ci;
        }
        float cmax = -INFINITY;
        #pragma unroll
        for (int mi = 0; mi < 4; ++mi)
            #pragma unroll
            for (int r = 0; r < 4; ++r)
                cmax = fmaxf(cmax, sv[mi][r]);
        cmax = fmaxf(cmax, __shfl_xor(cmax, 16));
        cmax = fmaxf(cmax, __shfl_xor(cmax, 32));
        float mnew = fmaxf(mrow, cmax);
        float corr = __builtin_exp2f(mrow - mnew);
        float psum = 0.f;
        f16x4 pf[4];
        #pragma unroll
        for (int mi = 0; mi < 4; ++mi) {
            #pragma unroll
            for (int r = 0; r < 4; ++r) {
                float pv = __builtin_exp2f(sv[mi][r] - mnew);
                psum += pv;
                pf[mi][r] = (_Float16)pv;
            }
        }
        psum += __shfl_xor(psum, 16);
        psum += __shfl_xor(psum, 32);
        lsum = lsum * corr + psum;
        mrow = mnew;
        O0 *= corr; O1 *= corr; O2 *= corr; O3 *= corr;

        #pragma unroll
        for (int mi = 0; mi < 4; ++mi) {
            int mo = mb + mi * 16 + q * 4;
            f16x4 v0 = *(const f16x4*)(Vg + (size_t)(t) * 2048 + mo);
            f16x4 v1 = *(const f16x4*)(Vg + (size_t)(16 + t) * 2048 + mo);
            f16x4 v2 = *(const f16x4*)(Vg + (size_t)(32 + t) * 2048 + mo);
            f16x4 v3 = *(const f16x4*)(Vg + (size_t)(48 + t) * 2048 + mo);
            O0 = __builtin_amdgcn_mfma_f32_16x16x16f16(v0, pf[mi], O0, 0, 0, 0);
            O1 = __builtin_amdgcn_mfma_f32_16x16x16f16(v1, pf[mi], O1, 0, 0, 0);
            O2 = __builtin_amdgcn_mfma_f32_16x16x16f16(v2, pf[mi], O2, 0, 0, 0);
            O3 = __builtin_amdgcn_mfma_f32_16x16x16f16(v3, pf[mi], O3, 0, 0, 0);
        }
    }
    size_t ob = (size_t)(u * 16 + t) * 64;
    *(f32x4*)(Opart + ob + q*4)      = O0;
    *(f32x4*)(Opart + ob + 16 + q*4) = O1;
    *(f32x4*)(Opart + ob + 32 + q*4) = O2;
    *(f32x4*)(Opart + ob + 48 + q*4) = O3;
    if (q == 0) { Mpart[u*16 + t] = mrow; Lpart[u*16 + t] = lsum; }
}

// ---------------- combine split-M partials, normalize, + Wv_b ----------------
__global__ __launch_bounds__(256) void mega_combine(
    const float* __restrict__ Opart, const float* __restrict__ Mpart,
    const float* __restrict__ Lpart, const float* __restrict__ Wv_b,
    float* __restrict__ outp)
{
    int idx = blockIdx.x * 256 + threadIdx.x;
    int n = idx >> 10, col = idx & 1023;
    int g = col >> 6, d = col & 63;
    int nt = n >> 4, t = n & 15;
    int u0 = (g * 32 + nt) * 4;
    float ms0 = Mpart[(u0+0)*16 + t], ms1 = Mpart[(u0+1)*16 + t],
          ms2 = Mpart[(u0+2)*16 + t], ms3 = Mpart[(u0+3)*16 + t];
    float M = fmaxf(fmaxf(ms0, ms1), fmaxf(ms2, ms3));
    float w0 = __builtin_exp2f(ms0 - M), w1 = __builtin_exp2f(ms1 - M),
          w2 = __builtin_exp2f(ms2 - M), w3 = __builtin_exp2f(ms3 - M);
    float accO = w0 * Opart[(size_t)((u0+0)*16 + t)*64 + d]
               + w1 * Opart[(size_t)((u0+1)*16 + t)*64 + d]
               + w2 * Opart[(size_t)((u0+2)*16 + t)*64 + d]
               + w3 * Opart[(size_t)((u0+3)*16 + t)*64 + d];
    float accL = w0 * Lpart[(u0+0)*16 + t] + w1 * Lpart[(u0+1)*16 + t]
               + w2 * Lpart[(u0+2)*16 + t] + w3 * Lpart[(u0+3)*16 + t];
    outp[idx] = accO / accL + Wv_b[col];
}

extern "C" void kernel_launch(void* const* d_in, const int* in_sizes, int n_in,
                              void* d_out, int out_size, void* d_ws, size_t ws_size,
                              hipStream_t stream)
{
    const float* bbox     = (const float*)d_in[0];
    const float* ref_bbox = (const float*)d_in[1];
    const float* roi_feat = (const float*)d_in[2];
    const float* ref_feat = (const float*)d_in[3];
    const float* Wg_w = (const float*)d_in[4];
    const float* Wg_b = (const float*)d_in[5];
    const float* Wq_w = (const float*)d_in[6];
    const float* Wq_b = (const float*)d_in[7];
    const float* Wk_w = (const float*)d_in[8];
    const float* Wk_b = (const float*)d_in[9];
    const float* Wv_w = (const float*)d_in[10];
    const float* Wv_b = (const float*)d_in[11];
    const float* uvec = (const float*)d_in[12];
    float* outp = (float*)d_out;
    char* ws = (char*)d_ws;

    // prior [512*16][2048] f16 occupies [0,32M) and overlays the f16 input copies,
    // which are dead after mega_gemm (prior is written after gemm completes).
    _Float16* prior = (_Float16*)ws;
    _Float16* roi_h = (_Float16*)(ws + 0);
    _Float16* ref_h = (_Float16*)(ws + (1ull<<20));
    _Float16* wq_h  = (_Float16*)(ws + (5ull<<20));
    _Float16* wk_h  = (_Float16*)(ws + (7ull<<20));
    _Float16* wv_h  = (_Float16*)(ws + (9ull<<20));
    size_t b2 = 32ull<<20;
    _Float16* wg_h  = (_Float16*)(ws + b2);
    float* qbias    = (float*)(ws + b2 + 4096);
    float* roig     = (float*)(ws + b2 + 8192);
    float* refg     = (float*)(ws + b2 + 24576);
    _Float16* Qh    = (_Float16*)(ws + b2 + 65536);
    _Float16* Kh    = (_Float16*)(ws + b2 + 65536 + (1ull<<20));
    _Float16* Vth   = (_Float16*)(ws + b2 + 65536 + (5ull<<20));
    float* Opart    = (float*)(ws + b2 + 65536 + (9ull<<20));
    float* Mpart    = (float*)(ws + b2 + 65536 + (17ull<<20));
    float* Lpart    = (float*)(ws + b2 + 65536 + (17ull<<20) + 131072);

    mega_prep<<<5644, 256, 0, stream>>>(bbox, ref_bbox, roi_feat, ref_feat,
        Wg_w, Wq_w, Wk_w, Wv_w, Wq_b, uvec,
        roi_h, ref_h, wq_h, wk_h, wv_h, wg_h, qbias, roig, refg);
    mega_gemm<<<288, 256, 0, stream>>>(roi_h, ref_h, wq_h, wk_h, wv_h,
        qbias, Wk_b, Qh, Kh, Vth);
    mega_prior<<<1024, 256, 0, stream>>>(wg_h, Wg_b, roig, refg, prior);
    mega_attn<<<512, 256, 0, stream>>>(Qh, Kh, Vth, prior, Opart, Mpart, Lpart);
    mega_combine<<<2048, 256, 0, stream>>>(Opart, Mpart, Lpart, Wv_b, outp);
}

// Round 2
// 192.306 us; speedup vs baseline: 1.0145x; 1.0145x over previous
//
#include <hip/hip_runtime.h>
#include <stdint.h>

typedef float f32x4 __attribute__((ext_vector_type(4)));
typedef _Float16 f16x8 __attribute__((ext_vector_type(8)));
typedef _Float16 f16x4 __attribute__((ext_vector_type(4)));

#define LOG2E 1.44269504088896340736f

// global -> LDS direct copy, 16B per lane, wave-uniform LDS base (guide §5)
__device__ __forceinline__ void gload_lds16(const void* g, void* l) {
    auto gp = reinterpret_cast<const uint32_t __attribute__((address_space(1)))*>(
        reinterpret_cast<uintptr_t>(g));
    auto lp = reinterpret_cast<uint32_t __attribute__((address_space(3)))*>(
        reinterpret_cast<uintptr_t>(l));
    __builtin_amdgcn_global_load_lds(gp, lp, 16, 0, 0);
}

// ---------------- prep: f32->f16 converts, qbias=Wq_b+u, bbox geometry ----------------
__global__ __launch_bounds__(256) void mega_prep(
    const float* __restrict__ bbox, const float* __restrict__ ref_bbox,
    const float* __restrict__ roi_feat, const float* __restrict__ ref_feat,
    const float* __restrict__ Wg_w, const float* __restrict__ Wq_w,
    const float* __restrict__ Wk_w, const float* __restrict__ Wv_w,
    const float* __restrict__ Wq_b, const float* __restrict__ uvec,
    _Float16* __restrict__ roi_h, _Float16* __restrict__ ref_h,
    _Float16* __restrict__ wq_h, _Float16* __restrict__ wk_h,
    _Float16* __restrict__ wv_h, _Float16* __restrict__ wg_h,
    float* __restrict__ qbias, float* __restrict__ roig, float* __restrict__ refg)
{
    int idx = blockIdx.x * 256 + threadIdx.x;
    if (idx < 1442048) {
        const float* src; _Float16* dst; int off;
        if (idx < 131072)       { src = roi_feat; dst = roi_h; off = idx; }
        else if (idx < 655360)  { src = ref_feat; dst = ref_h; off = idx - 131072; }
        else if (idx < 917504)  { src = Wq_w;     dst = wq_h;  off = idx - 655360; }
        else if (idx < 1179648) { src = Wk_w;     dst = wk_h;  off = idx - 917504; }
        else if (idx < 1441792) { src = Wv_w;     dst = wv_h;  off = idx - 1179648; }
        else                    { src = Wg_w;     dst = wg_h;  off = idx - 1441792; }
        f32x4 v = *(const f32x4*)(src + (size_t)off * 4);
        f16x4 o;
        o[0] = (_Float16)v[0]; o[1] = (_Float16)v[1];
        o[2] = (_Float16)v[2]; o[3] = (_Float16)v[3];
        *(f16x4*)(dst + (size_t)off * 4) = o;
    } else if (idx < 1442304) {
        int off = idx - 1442048;
        f32x4 a = *(const f32x4*)(Wq_b + off * 4);
        f32x4 b = *(const f32x4*)(uvec + off * 4);
        f32x4 r = a + b;
        *(f32x4*)(qbias + off * 4) = r;
    } else if (idx < 1442816) {
        int n = idx - 1442304;
        f32x4 bb = *(const f32x4*)(bbox + n * 4);
        float w = bb[2] - bb[0] + 1.0f, h = bb[3] - bb[1] + 1.0f;
        f32x4 o1 = {0.5f*(bb[0]+bb[2]), 0.5f*(bb[1]+bb[3]), 1.0f/w, 1.0f/h};
        f32x4 o2 = {__logf(w), __logf(h), 0.f, 0.f};
        *(f32x4*)(roig + n*8) = o1;
        *(f32x4*)(roig + n*8 + 4) = o2;
    } else if (idx < 1444864) {
        int m = idx - 1442816;
        f32x4 bb = *(const f32x4*)(ref_bbox + m * 4);
        float w = bb[2] - bb[0] + 1.0f, h = bb[3] - bb[1] + 1.0f;
        f32x4 o = {0.5f*(bb[0]+bb[2]), 0.5f*(bb[1]+bb[3]), __logf(w), __logf(h)};
        *(f32x4*)(refg + m*4) = o;
    }
}

// ---------------- batched QKV GEMM: C = A*B^T (+bias)*scale, 64x128 tile ----------------
// b<64:  Q = roi@Wq^T, scaled 0.125*log2e, bias=Wq_b+u -> Qg [16][512][64]  (g-blocked)
// b<320: K = ref@Wk^T + Wk_b                           -> Kg [16][2048][64] (g-blocked)
// else:  V = ref@Wv'^T                                  -> Vth [1024][2048]  (transposed)
__global__ __launch_bounds__(256) void mega_gemm(
    const _Float16* __restrict__ roi_h, const _Float16* __restrict__ ref_h,
    const _Float16* __restrict__ wq_h, const _Float16* __restrict__ wk_h,
    const _Float16* __restrict__ wv_h, const float* __restrict__ qbias,
    const float* __restrict__ Wk_b,
    _Float16* __restrict__ Qg, _Float16* __restrict__ Kg, _Float16* __restrict__ Vth)
{
    __shared__ _Float16 As[64 * 32];
    __shared__ _Float16 Bs[128 * 32];

    int b = blockIdx.x;
    const _Float16 *A, *B;
    const float* bias;
    _Float16* out;
    int tm, tn, mode, MR; float scale;
    if (b < 64)       { A = roi_h; B = wq_h; bias = qbias; out = Qg;  tm = b >> 3;        tn = b & 7;       mode = 0; MR = 512;  scale = 0.125f * LOG2E; }
    else if (b < 320) { A = ref_h; B = wk_h; bias = Wk_b;  out = Kg;  tm = (b-64) >> 3;   tn = (b-64) & 7;  mode = 0; MR = 2048; scale = 1.f; }
    else              { A = ref_h; B = wv_h; bias = nullptr; out = Vth; tm = (b-320) >> 3; tn = (b-320) & 7; mode = 1; MR = 2048; scale = 1.f; }

    int tid = threadIdx.x;
    int w = tid >> 6, l = tid & 63, q = l >> 4, t = l & 15;
    int wm = w >> 1, wn = w & 1;
    int m0 = tm * 64, n0 = tn * 128;

    const _Float16* gA  = A + (size_t)(m0 + w*16 + (l >> 2)) * 1024 + (l & 3) * 8;
    const _Float16* gB  = B + (size_t)(n0 + w*16 + (l >> 2)) * 1024 + (l & 3) * 8;
    const _Float16* gB2 = gB + 64 * 1024;
    _Float16* lA  = &As[w * 512];
    _Float16* lB  = &Bs[w * 512];
    _Float16* lB2 = &Bs[2048 + w * 512];

    f32x4 acc[2][4];
    #pragma unroll
    for (int i = 0; i < 2; ++i)
        #pragma unroll
        for (int j = 0; j < 4; ++j)
            acc[i][j] = (f32x4){0.f, 0.f, 0.f, 0.f};

    for (int k0 = 0; k0 < 1024; k0 += 32) {
        gload_lds16(gA + k0, lA);
        gload_lds16(gB + k0, lB);
        gload_lds16(gB2 + k0, lB2);
        __syncthreads();
        f16x8 af[2], bfv[4];
        #pragma unroll
        for (int i = 0; i < 2; ++i)
            af[i]  = *(const f16x8*)&As[(wm*32 + i*16 + t) * 32 + q*8];
        #pragma unroll
        for (int j = 0; j < 4; ++j)
            bfv[j] = *(const f16x8*)&Bs[(wn*64 + j*16 + t) * 32 + q*8];
        #pragma unroll
        for (int mi = 0; mi < 2; ++mi)
            #pragma unroll
            for (int ni = 0; ni < 4; ++ni)
                acc[mi][ni] = __builtin_amdgcn_mfma_f32_16x16x32_f16(af[mi], bfv[ni], acc[mi][ni], 0, 0, 0);
        __syncthreads();
    }

    #pragma unroll
    for (int mi = 0; mi < 2; ++mi) {
        #pragma unroll
        for (int ni = 0; ni < 4; ++ni) {
            int col  = n0 + wn*64 + ni*16 + t;
            int row0 = m0 + wm*32 + mi*16 + q*4;
            f32x4 a = acc[mi][ni];
            if (mode == 0) {
                // g-blocked: out[g][row][d], g = col>>6, d = col&63
                float bb = bias[col];
                _Float16* op = out + ((size_t)(col >> 6) * MR + row0) * 64 + (col & 63);
                #pragma unroll
                for (int r = 0; r < 4; ++r)
                    op[(size_t)r * 64] = (_Float16)((a[r] + bb) * scale);
            } else {
                f16x4 pk;
                pk[0] = (_Float16)a[0]; pk[1] = (_Float16)a[1];
                pk[2] = (_Float16)a[2]; pk[3] = (_Float16)a[3];
                *(f16x4*)(out + (size_t)col * 2048 + row0) = pk;
            }
        }
    }
}

// ---------------- position prior: relu(Wg @ emb + Wg_b), via MFMA ----------------
__global__ __launch_bounds__(256) void mega_prior(
    const _Float16* __restrict__ wg_h, const float* __restrict__ Wg_b,
    const float* __restrict__ roig, const float* __restrict__ refg,
    _Float16* __restrict__ prior)
{
    int tid = threadIdx.x;
    int w = tid >> 6, l = tid & 63, q = l >> 4, p = l & 15;
    int n = blockIdx.x >> 1, half = blockIdx.x & 1;

    f16x8 wa0 = *(const f16x8*)(wg_h + p*64 + q*8);
    f16x8 wa1 = *(const f16x8*)(wg_h + p*64 + 32 + q*8);
    f32x4 wb = *(const f32x4*)(Wg_b + q*4);

    f32x4 rg1 = *(const f32x4*)(roig + n*8);
    f32x4 rg2 = *(const f32x4*)(roig + n*8 + 4);

    float cf[8];
    #pragma unroll
    for (int f = 0; f < 8; ++f)
        cf[f] = 15.9154943091895336f * __builtin_exp2f(-1.24572303558276059f * (float)f);

    float coff = (q & 1) ? 0.25f : 0.0f;   // cos(x) = sin(x + 1/4 rev)
    bool isX = (q < 2);

    int mstart = half * 1024 + w * 256;
    for (int it = 0; it < 16; ++it) {
        int m = mstart + it * 16 + p;
        f32x4 rg = *(const f32x4*)(refg + m * 4);
        float posA = isX ? __logf(fabsf(rg1[0] - rg[0]) * rg1[2] + 1e-3f)
                         : __logf(fabsf(rg1[1] - rg[1]) * rg1[3] + 1e-3f);
        float posB = isX ? (rg2[0] - rg[2]) : (rg2[1] - rg[3]);
        f16x8 e0, e1;
        #pragma unroll
        for (int f = 0; f < 8; ++f) {
            float a0 = posA * cf[f] + coff; a0 -= floorf(a0);
            float a1 = posB * cf[f] + coff; a1 -= floorf(a1);
            e0[f] = (_Float16)__builtin_amdgcn_sinf(a0);
            e1[f] = (_Float16)__builtin_amdgcn_sinf(a1);
        }
        f32x4 acc = wb;
        acc = __builtin_amdgcn_mfma_f32_16x16x32_f16(wa0, e0, acc, 0, 0, 0);
        acc = __builtin_amdgcn_mfma_f32_16x16x32_f16(wa1, e1, acc, 0, 0, 0);
        _Float16* pp = prior + (size_t)(n * 16) * 2048 + m;
        #pragma unroll
        for (int r = 0; r < 4; ++r)
            pp[(size_t)(q*4 + r) * 2048] = (_Float16)fmaxf(acc[r], 0.f);
    }
}

// ---------------- flash attention, per-wave unit = (g, 16 n-rows, m-eighth of 256) ----------------
__global__ __launch_bounds__(256, 4) void mega_attn(
    const _Float16* __restrict__ Qg, const _Float16* __restrict__ Kg,
    const _Float16* __restrict__ Vth, const _Float16* __restrict__ prior,
    float* __restrict__ Opart, float* __restrict__ Mpart, float* __restrict__ Lpart)
{
    int u = blockIdx.x * 4 + (threadIdx.x >> 6);
    int l = threadIdx.x & 63, q = l >> 4, t = l & 15;
    int g = u >> 8, nt = (u >> 3) & 31, s = u & 7;
    int n = nt * 16 + t;

    const _Float16* Qrow = Qg + (size_t)(g * 512 + n) * 64;
    f16x8 qf0 = *(const f16x8*)(Qrow + q * 8);
    f16x8 qf1 = *(const f16x8*)(Qrow + 32 + q * 8);

    const _Float16* Pb = prior + (size_t)(n * 16 + g) * 2048 + s * 256;
    const _Float16* Kb = Kg + ((size_t)g * 2048 + s * 256) * 64;
    const _Float16* Vg = Vth + (size_t)(g * 64) * 2048 + s * 256;

    float mrow = -INFINITY, lsum = 0.f;
    f32x4 O0 = {0,0,0,0}, O1 = {0,0,0,0}, O2 = {0,0,0,0}, O3 = {0,0,0,0};

    for (int c = 0; c < 4; ++c) {
        int mb = c * 64;
        // prior loads issued first (latency hides under QK MFMAs)
        f16x4 pr[4];
        #pragma unroll
        for (int mi = 0; mi < 4; ++mi)
            pr[mi] = *(const f16x4*)(Pb + mb + mi * 16 + q * 4);
        // QK^T with C=0 (no dependency on prior load)
        f32x4 sv[4];
        #pragma unroll
        for (int mi = 0; mi < 4; ++mi) {
            const _Float16* Krow = Kb + (size_t)(mb + mi * 16 + t) * 64;
            f16x8 k0 = *(const f16x8*)(Krow + q * 8);
            f16x8 k1 = *(const f16x8*)(Krow + 32 + q * 8);
            f32x4 z = {0,0,0,0};
            z = __builtin_amdgcn_mfma_f32_16x16x32_f16(k0, qf0, z, 0, 0, 0);
            z = __builtin_amdgcn_mfma_f32_16x16x32_f16(k1, qf1, z, 0, 0, 0);
            sv[mi] = z;
        }
        #pragma unroll
        for (int mi = 0; mi < 4; ++mi)
            #pragma unroll
            for (int r = 0; r < 4; ++r)
                sv[mi][r] += __log2f((float)pr[mi][r] + 1e-6f);
        // V loads issued before softmax; latency hides under shuffles/exp2
        f16x4 vv[4][4];
        #pragma unroll
        for (int i = 0; i < 4; ++i)
            #pragma unroll
            for (int mi = 0; mi < 4; ++mi)
                vv[i][mi] = *(const f16x4*)(Vg + (size_t)(i * 16 + t) * 2048 + mb + mi * 16 + q * 4);
        // online softmax (log2 domain)
        float cmax = -INFINITY;
        #pragma unroll
        for (int mi = 0; mi < 4; ++mi)
            #pragma unroll
            for (int r = 0; r < 4; ++r)
                cmax = fmaxf(cmax, sv[mi][r]);
        cmax = fmaxf(cmax, __shfl_xor(cmax, 16));
        cmax = fmaxf(cmax, __shfl_xor(cmax, 32));
        float mnew = fmaxf(mrow, cmax);
        float corr = __builtin_exp2f(mrow - mnew);
        float psum = 0.f;
        f16x4 pf[4];
        #pragma unroll
        for (int mi = 0; mi < 4; ++mi) {
            #pragma unroll
            for (int r = 0; r < 4; ++r) {
                float pv = __builtin_exp2f(sv[mi][r] - mnew);
                psum += pv;
                pf[mi][r] = (_Float16)pv;
            }
        }
        psum += __shfl_xor(psum, 16);
        psum += __shfl_xor(psum, 32);
        lsum = lsum * corr + psum;
        mrow = mnew;
        O0 *= corr; O1 *= corr; O2 *= corr; O3 *= corr;
        #pragma unroll
        for (int mi = 0; mi < 4; ++mi) {
            O0 = __builtin_amdgcn_mfma_f32_16x16x16f16(vv[0][mi], pf[mi], O0, 0, 0, 0);
            O1 = __builtin_amdgcn_mfma_f32_16x16x16f16(vv[1][mi], pf[mi], O1, 0, 0, 0);
            O2 = __builtin_amdgcn_mfma_f32_16x16x16f16(vv[2][mi], pf[mi], O2, 0, 0, 0);
            O3 = __builtin_amdgcn_mfma_f32_16x16x16f16(vv[3][mi], pf[mi], O3, 0, 0, 0);
        }
    }
    size_t ob = (size_t)(u * 16 + t) * 64;
    *(f32x4*)(Opart + ob + q*4)      = O0;
    *(f32x4*)(Opart + ob + 16 + q*4) = O1;
    *(f32x4*)(Opart + ob + 32 + q*4) = O2;
    *(f32x4*)(Opart + ob + 48 + q*4) = O3;
    if (q == 0) { Mpart[u*16 + t] = mrow; Lpart[u*16 + t] = lsum; }
}

// ---------------- combine 8 split-M partials, normalize, + Wv_b ----------------
__global__ __launch_bounds__(256) void mega_combine(
    const float* __restrict__ Opart, const float* __restrict__ Mpart,
    const float* __restrict__ Lpart, const float* __restrict__ Wv_b,
    float* __restrict__ outp)
{
    int idx = blockIdx.x * 256 + threadIdx.x;
    int n = idx >> 10, col = idx & 1023;
    int g = col >> 6, d = col & 63;
    int nt = n >> 4, t = n & 15;
    int u0 = ((g * 32 + nt) << 3);
    float ms[8];
    #pragma unroll
    for (int s = 0; s < 8; ++s) ms[s] = Mpart[(u0 + s) * 16 + t];
    float M = ms[0];
    #pragma unroll
    for (int s = 1; s < 8; ++s) M = fmaxf(M, ms[s]);
    float accO = 0.f, accL = 0.f;
    #pragma unroll
    for (int s = 0; s < 8; ++s) {
        float wgt = __builtin_exp2f(ms[s] - M);
        accO += wgt * Opart[(size_t)((u0 + s) * 16 + t) * 64 + d];
        accL += wgt * Lpart[(u0 + s) * 16 + t];
    }
    outp[idx] = accO / accL + Wv_b[col];
}

extern "C" void kernel_launch(void* const* d_in, const int* in_sizes, int n_in,
                              void* d_out, int out_size, void* d_ws, size_t ws_size,
                              hipStream_t stream)
{
    const float* bbox     = (const float*)d_in[0];
    const float* ref_bbox = (const float*)d_in[1];
    const float* roi_feat = (const float*)d_in[2];
    const float* ref_feat = (const float*)d_in[3];
    const float* Wg_w = (const float*)d_in[4];
    const float* Wg_b = (const float*)d_in[5];
    const float* Wq_w = (const float*)d_in[6];
    const float* Wq_b = (const float*)d_in[7];
    const float* Wk_w = (const float*)d_in[8];
    const float* Wk_b = (const float*)d_in[9];
    const float* Wv_w = (const float*)d_in[10];
    const float* Wv_b = (const float*)d_in[11];
    const float* uvec = (const float*)d_in[12];
    float* outp = (float*)d_out;
    char* ws = (char*)d_ws;

    // prior [512*16][2048] f16 occupies [0,32M) and overlays the f16 input copies,
    // which are dead after mega_gemm (prior is written after gemm completes).
    _Float16* prior = (_Float16*)ws;
    _Float16* roi_h = (_Float16*)(ws + 0);
    _Float16* ref_h = (_Float16*)(ws + (1ull<<20));
    _Float16* wq_h  = (_Float16*)(ws + (5ull<<20));
    _Float16* wk_h  = (_Float16*)(ws + (7ull<<20));
    _Float16* wv_h  = (_Float16*)(ws + (9ull<<20));
    size_t b2 = 32ull<<20;
    _Float16* wg_h  = (_Float16*)(ws + b2);
    float* qbias    = (float*)(ws + b2 + 4096);
    float* roig     = (float*)(ws + b2 + 8192);
    float* refg     = (float*)(ws + b2 + 24576);
    _Float16* Qh    = (_Float16*)(ws + b2 + 65536);
    _Float16* Kh    = (_Float16*)(ws + b2 + 65536 + (1ull<<20));
    _Float16* Vth   = (_Float16*)(ws + b2 + 65536 + (5ull<<20));
    float* Opart    = (float*)(ws + b2 + 65536 + (9ull<<20));
    float* Mpart    = (float*)(ws + b2 + 65536 + (25ull<<20));
    float* Lpart    = (float*)(ws + b2 + 65536 + (25ull<<20) + 262144);

    mega_prep<<<5644, 256, 0, stream>>>(bbox, ref_bbox, roi_feat, ref_feat,
        Wg_w, Wq_w, Wk_w, Wv_w, Wq_b, uvec,
        roi_h, ref_h, wq_h, wk_h, wv_h, wg_h, qbias, roig, refg);
    mega_gemm<<<576, 256, 0, stream>>>(roi_h, ref_h, wq_h, wk_h, wv_h,
        qbias, Wk_b, Qh, Kh, Vth);
    mega_prior<<<1024, 256, 0, stream>>>(wg_h, Wg_b, roig, refg, prior);
    mega_attn<<<1024, 256, 0, stream>>>(Qh, Kh, Vth, prior, Opart, Mpart, Lpart);
    mega_combine<<<2048, 256, 0, stream>>>(Opart, Mpart, Lpart, Wv_b, outp);
}

// Round 3
// 161.911 us; speedup vs baseline: 1.2049x; 1.1877x over previous
//
#include <hip/hip_runtime.h>
#include <stdint.h>

typedef float f32x4 __attribute__((ext_vector_type(4)));
typedef _Float16 f16x8 __attribute__((ext_vector_type(8)));
typedef _Float16 f16x4 __attribute__((ext_vector_type(4)));
typedef int int4v __attribute__((ext_vector_type(4)));

#define LOG2E 1.44269504088896340736f

// global -> LDS direct copy, 16B per lane, wave-uniform LDS base (guide §5)
__device__ __forceinline__ void gload_lds16(const void* g, void* l) {
    auto gp = reinterpret_cast<const uint32_t __attribute__((address_space(1)))*>(
        reinterpret_cast<uintptr_t>(g));
    auto lp = reinterpret_cast<uint32_t __attribute__((address_space(3)))*>(
        reinterpret_cast<uintptr_t>(l));
    __builtin_amdgcn_global_load_lds(gp, lp, 16, 0, 0);
}

// ---------------- prep: f32->f16 converts, qbias=Wq_b+u, bbox geometry ----------------
__global__ __launch_bounds__(256) void mega_prep(
    const float* __restrict__ bbox, const float* __restrict__ ref_bbox,
    const float* __restrict__ roi_feat, const float* __restrict__ ref_feat,
    const float* __restrict__ Wg_w, const float* __restrict__ Wq_w,
    const float* __restrict__ Wk_w, const float* __restrict__ Wv_w,
    const float* __restrict__ Wq_b, const float* __restrict__ uvec,
    _Float16* __restrict__ roi_h, _Float16* __restrict__ ref_h,
    _Float16* __restrict__ wq_h, _Float16* __restrict__ wk_h,
    _Float16* __restrict__ wv_h, _Float16* __restrict__ wg_h,
    float* __restrict__ qbias, float* __restrict__ roig, float* __restrict__ refg)
{
    int idx = blockIdx.x * 256 + threadIdx.x;
    if (idx < 1442048) {
        const float* src; _Float16* dst; int off;
        if (idx < 131072)       { src = roi_feat; dst = roi_h; off = idx; }
        else if (idx < 655360)  { src = ref_feat; dst = ref_h; off = idx - 131072; }
        else if (idx < 917504)  { src = Wq_w;     dst = wq_h;  off = idx - 655360; }
        else if (idx < 1179648) { src = Wk_w;     dst = wk_h;  off = idx - 917504; }
        else if (idx < 1441792) { src = Wv_w;     dst = wv_h;  off = idx - 1179648; }
        else                    { src = Wg_w;     dst = wg_h;  off = idx - 1441792; }
        f32x4 v = *(const f32x4*)(src + (size_t)off * 4);
        f16x4 o;
        o[0] = (_Float16)v[0]; o[1] = (_Float16)v[1];
        o[2] = (_Float16)v[2]; o[3] = (_Float16)v[3];
        *(f16x4*)(dst + (size_t)off * 4) = o;
    } else if (idx < 1442304) {
        int off = idx - 1442048;
        f32x4 a = *(const f32x4*)(Wq_b + off * 4);
        f32x4 b = *(const f32x4*)(uvec + off * 4);
        f32x4 r = a + b;
        *(f32x4*)(qbias + off * 4) = r;
    } else if (idx < 1442816) {
        int n = idx - 1442304;
        f32x4 bb = *(const f32x4*)(bbox + n * 4);
        float w = bb[2] - bb[0] + 1.0f, h = bb[3] - bb[1] + 1.0f;
        f32x4 o1 = {0.5f*(bb[0]+bb[2]), 0.5f*(bb[1]+bb[3]), 1.0f/w, 1.0f/h};
        f32x4 o2 = {__logf(w), __logf(h), 0.f, 0.f};
        *(f32x4*)(roig + n*8) = o1;
        *(f32x4*)(roig + n*8 + 4) = o2;
    } else if (idx < 1444864) {
        int m = idx - 1442816;
        f32x4 bb = *(const f32x4*)(ref_bbox + m * 4);
        float w = bb[2] - bb[0] + 1.0f, h = bb[3] - bb[1] + 1.0f;
        f32x4 o = {0.5f*(bb[0]+bb[2]), 0.5f*(bb[1]+bb[3]), __logf(w), __logf(h)};
        *(f32x4*)(refg + m*4) = o;
    }
}

// ---------------- batched QKV GEMM: C = A*B^T (+bias)*scale, 64x128 tile ----------------
// b<64:  Q = roi@Wq^T, scaled 0.125*log2e, bias=Wq_b+u -> Qg [16][512][64]  (g-blocked)
// b<320: K = ref@Wk^T + Wk_b                           -> Kg [16][2048][64] (g-blocked)
// else:  V = ref@Wv'^T                                  -> Vth [1024][2048]  (transposed)
__global__ __launch_bounds__(256) void mega_gemm(
    const _Float16* __restrict__ roi_h, const _Float16* __restrict__ ref_h,
    const _Float16* __restrict__ wq_h, const _Float16* __restrict__ wk_h,
    const _Float16* __restrict__ wv_h, const float* __restrict__ qbias,
    const float* __restrict__ Wk_b,
    _Float16* __restrict__ Qg, _Float16* __restrict__ Kg, _Float16* __restrict__ Vth)
{
    __shared__ _Float16 As[64 * 32];
    __shared__ _Float16 Bs[128 * 32];

    int b = blockIdx.x;
    const _Float16 *A, *B;
    const float* bias;
    _Float16* out;
    int tm, tn, mode, MR; float scale;
    if (b < 64)       { A = roi_h; B = wq_h; bias = qbias; out = Qg;  tm = b >> 3;        tn = b & 7;       mode = 0; MR = 512;  scale = 0.125f * LOG2E; }
    else if (b < 320) { A = ref_h; B = wk_h; bias = Wk_b;  out = Kg;  tm = (b-64) >> 3;   tn = (b-64) & 7;  mode = 0; MR = 2048; scale = 1.f; }
    else              { A = ref_h; B = wv_h; bias = nullptr; out = Vth; tm = (b-320) >> 3; tn = (b-320) & 7; mode = 1; MR = 2048; scale = 1.f; }

    int tid = threadIdx.x;
    int w = tid >> 6, l = tid & 63, q = l >> 4, t = l & 15;
    int wm = w >> 1, wn = w & 1;
    int m0 = tm * 64, n0 = tn * 128;

    const _Float16* gA  = A + (size_t)(m0 + w*16 + (l >> 2)) * 1024 + (l & 3) * 8;
    const _Float16* gB  = B + (size_t)(n0 + w*16 + (l >> 2)) * 1024 + (l & 3) * 8;
    const _Float16* gB2 = gB + 64 * 1024;
    _Float16* lA  = &As[w * 512];
    _Float16* lB  = &Bs[w * 512];
    _Float16* lB2 = &Bs[2048 + w * 512];

    f32x4 acc[2][4];
    #pragma unroll
    for (int i = 0; i < 2; ++i)
        #pragma unroll
        for (int j = 0; j < 4; ++j)
            acc[i][j] = (f32x4){0.f, 0.f, 0.f, 0.f};

    for (int k0 = 0; k0 < 1024; k0 += 32) {
        gload_lds16(gA + k0, lA);
        gload_lds16(gB + k0, lB);
        gload_lds16(gB2 + k0, lB2);
        __syncthreads();
        f16x8 af[2], bfv[4];
        #pragma unroll
        for (int i = 0; i < 2; ++i)
            af[i]  = *(const f16x8*)&As[(wm*32 + i*16 + t) * 32 + q*8];
        #pragma unroll
        for (int j = 0; j < 4; ++j)
            bfv[j] = *(const f16x8*)&Bs[(wn*64 + j*16 + t) * 32 + q*8];
        #pragma unroll
        for (int mi = 0; mi < 2; ++mi)
            #pragma unroll
            for (int ni = 0; ni < 4; ++ni)
                acc[mi][ni] = __builtin_amdgcn_mfma_f32_16x16x32_f16(af[mi], bfv[ni], acc[mi][ni], 0, 0, 0);
        __syncthreads();
    }

    #pragma unroll
    for (int mi = 0; mi < 2; ++mi) {
        #pragma unroll
        for (int ni = 0; ni < 4; ++ni) {
            int col  = n0 + wn*64 + ni*16 + t;
            int row0 = m0 + wm*32 + mi*16 + q*4;
            f32x4 a = acc[mi][ni];
            if (mode == 0) {
                // g-blocked: out[g][row][d], g = col>>6, d = col&63
                float bb = bias[col];
                _Float16* op = out + ((size_t)(col >> 6) * MR + row0) * 64 + (col & 63);
                #pragma unroll
                for (int r = 0; r < 4; ++r)
                    op[(size_t)r * 64] = (_Float16)((a[r] + bb) * scale);
            } else {
                f16x4 pk;
                pk[0] = (_Float16)a[0]; pk[1] = (_Float16)a[1];
                pk[2] = (_Float16)a[2]; pk[3] = (_Float16)a[3];
                *(f16x4*)(out + (size_t)col * 2048 + row0) = pk;
            }
        }
    }
}

// ---------------- position prior: relu(Wg @ emb + Wg_b), via MFMA ----------------
// output layout [g][n][m] f16: prior[g*512*2048 + n*2048 + m]
__global__ __launch_bounds__(256) void mega_prior(
    const _Float16* __restrict__ wg_h, const float* __restrict__ Wg_b,
    const float* __restrict__ roig, const float* __restrict__ refg,
    _Float16* __restrict__ prior)
{
    int tid = threadIdx.x;
    int w = tid >> 6, l = tid & 63, q = l >> 4, p = l & 15;
    int n = blockIdx.x >> 1, half = blockIdx.x & 1;

    f16x8 wa0 = *(const f16x8*)(wg_h + p*64 + q*8);
    f16x8 wa1 = *(const f16x8*)(wg_h + p*64 + 32 + q*8);
    f32x4 wb = *(const f32x4*)(Wg_b + q*4);

    f32x4 rg1 = *(const f32x4*)(roig + n*8);
    f32x4 rg2 = *(const f32x4*)(roig + n*8 + 4);

    float cf[8];
    #pragma unroll
    for (int f = 0; f < 8; ++f)
        cf[f] = 15.9154943091895336f * __builtin_exp2f(-1.24572303558276059f * (float)f);

    float coff = (q & 1) ? 0.25f : 0.0f;   // cos(x) = sin(x + 1/4 rev)
    bool isX = (q < 2);

    int mstart = half * 1024 + w * 256;
    for (int it = 0; it < 16; ++it) {
        int m = mstart + it * 16 + p;
        f32x4 rg = *(const f32x4*)(refg + m * 4);
        float posA = isX ? __logf(fabsf(rg1[0] - rg[0]) * rg1[2] + 1e-3f)
                         : __logf(fabsf(rg1[1] - rg[1]) * rg1[3] + 1e-3f);
        float posB = isX ? (rg2[0] - rg[2]) : (rg2[1] - rg[3]);
        f16x8 e0, e1;
        #pragma unroll
        for (int f = 0; f < 8; ++f) {
            float a0 = posA * cf[f] + coff; a0 -= floorf(a0);
            float a1 = posB * cf[f] + coff; a1 -= floorf(a1);
            e0[f] = (_Float16)__builtin_amdgcn_sinf(a0);
            e1[f] = (_Float16)__builtin_amdgcn_sinf(a1);
        }
        f32x4 acc = wb;
        acc = __builtin_amdgcn_mfma_f32_16x16x32_f16(wa0, e0, acc, 0, 0, 0);
        acc = __builtin_amdgcn_mfma_f32_16x16x32_f16(wa1, e1, acc, 0, 0, 0);
        _Float16* pp = prior + (size_t)n * 2048 + m;
        #pragma unroll
        for (int r = 0; r < 4; ++r)
            pp[(size_t)(q*4 + r) * 1048576] = (_Float16)fmaxf(acc[r], 0.f);
    }
}

// ---------------- flash attention, LDS-staged ----------------
// block = 4 waves = (g, 64 n rows, 256-m span). Per 64-m chunk: stage
// K[64][64], V^T[64][64], prior[64][64] into LDS (coalesced, XOR-swizzled),
// async-split staging (T14): next chunk's global loads issued before compute.
#define SWZ(row, cb) ((cb) ^ (((row) & 7) << 4))

__device__ __forceinline__ f16x8 ld128s(const _Float16* base, int row, int cb) {
    return *(const f16x8*)((const char*)base + row * 128 + SWZ(row, cb));
}
__device__ __forceinline__ f16x4 ld64s(const _Float16* base, int row, int cb) {
    return *(const f16x4*)((const char*)base + row * 128 + SWZ(row, cb));
}

__global__ __launch_bounds__(256, 4) void mega_attn(
    const _Float16* __restrict__ Qg, const _Float16* __restrict__ Kg,
    const _Float16* __restrict__ Vth, const _Float16* __restrict__ prior,
    float* __restrict__ Opart, float* __restrict__ Mpart, float* __restrict__ Lpart)
{
    __shared__ __align__(16) _Float16 Kl[4096];
    __shared__ __align__(16) _Float16 Vl[4096];
    __shared__ __align__(16) _Float16 Pl[4096];

    int bid = blockIdx.x;
    int g = bid >> 6, nt4 = (bid >> 3) & 7, s = bid & 7;
    int tid = threadIdx.x;
    int w = tid >> 6, l = tid & 63, q = l >> 4, t = l & 15;
    int n0 = nt4 * 64, m0 = s * 256;

    int n = n0 + w * 16 + t;
    const _Float16* Qrow = Qg + ((size_t)g * 512 + n) * 64;
    f16x8 qf0 = *(const f16x8*)(Qrow + q * 8);
    f16x8 qf1 = *(const f16x8*)(Qrow + 32 + q * 8);

    // staging lane mapping: row r = tid/8 (+32), 16B chunk c8 = tid%8
    int r_lo = tid >> 3, c8 = tid & 7;
    const char* gK = (const char*)(Kg + ((size_t)g * 2048 + m0) * 64);
    const char* gV = (const char*)(Vth + (size_t)g * 64 * 2048 + m0);
    const char* gP = (const char*)(prior + ((size_t)g * 512 + n0) * 2048 + m0);

    int4v kr0, kr1, vr0, vr1, pq0, pq1;
#define LOADC(c) { \
    kr0 = *(const int4v*)(gK + (c)*8192 + r_lo*128 + c8*16); \
    kr1 = *(const int4v*)(gK + (c)*8192 + (r_lo+32)*128 + c8*16); \
    vr0 = *(const int4v*)(gV + (c)*128 + (size_t)r_lo*4096 + c8*16); \
    vr1 = *(const int4v*)(gV + (c)*128 + (size_t)(r_lo+32)*4096 + c8*16); \
    pq0 = *(const int4v*)(gP + (c)*128 + (size_t)r_lo*4096 + c8*16); \
    pq1 = *(const int4v*)(gP + (c)*128 + (size_t)(r_lo+32)*4096 + c8*16); }
#define WRITEC() { \
    int cb = c8 * 16, sw = SWZ(r_lo, cb); \
    *(int4v*)((char*)Kl + r_lo*128 + sw) = kr0; \
    *(int4v*)((char*)Kl + (r_lo+32)*128 + sw) = kr1; \
    *(int4v*)((char*)Vl + r_lo*128 + sw) = vr0; \
    *(int4v*)((char*)Vl + (r_lo+32)*128 + sw) = vr1; \
    *(int4v*)((char*)Pl + r_lo*128 + sw) = pq0; \
    *(int4v*)((char*)Pl + (r_lo+32)*128 + sw) = pq1; }

    float mrow = -INFINITY, lsum = 0.f;
    f32x4 O0 = {0,0,0,0}, O1 = {0,0,0,0}, O2 = {0,0,0,0}, O3 = {0,0,0,0};

    LOADC(0);
    for (int c = 0; c < 4; ++c) {
        __syncthreads();   // previous chunk's LDS reads done
        WRITEC();
        __syncthreads();   // chunk c staged
        if (c < 3) LOADC(c + 1);   // prefetch next chunk (hides under compute)

        // prior fragments (LDS, conflict-balanced b64)
        f16x4 pr[4];
        #pragma unroll
        for (int mi = 0; mi < 4; ++mi)
            pr[mi] = ld64s(Pl, w * 16 + t, mi * 32 + q * 8);
        // QK^T: A-frag = K rows, B-frag = Q (regs)
        f32x4 sv[4];
        #pragma unroll
        for (int mi = 0; mi < 4; ++mi) {
            f16x8 k0 = ld128s(Kl, mi * 16 + t, q * 16);
            f16x8 k1 = ld128s(Kl, mi * 16 + t, 64 + q * 16);
            f32x4 z = {0, 0, 0, 0};
            z = __builtin_amdgcn_mfma_f32_16x16x32_f16(k0, qf0, z, 0, 0, 0);
            z = __builtin_amdgcn_mfma_f32_16x16x32_f16(k1, qf1, z, 0, 0, 0);
            sv[mi] = z;
        }
        #pragma unroll
        for (int mi = 0; mi < 4; ++mi)
            #pragma unroll
            for (int r = 0; r < 4; ++r)
                sv[mi][r] += __log2f((float)pr[mi][r] + 1e-6f);
        // V fragments
        f16x4 vv[4][4];
        #pragma unroll
        for (int i = 0; i < 4; ++i)
            #pragma unroll
            for (int mi = 0; mi < 4; ++mi)
                vv[i][mi] = ld64s(Vl, i * 16 + t, mi * 32 + q * 8);
        // online softmax (log2 domain)
        float cmax = -INFINITY;
        #pragma unroll
        for (int mi = 0; mi < 4; ++mi)
            #pragma unroll
            for (int r = 0; r < 4; ++r)
                cmax = fmaxf(cmax, sv[mi][r]);
        cmax = fmaxf(cmax, __shfl_xor(cmax, 16));
        cmax = fmaxf(cmax, __shfl_xor(cmax, 32));
        float mnew = fmaxf(mrow, cmax);
        float corr = __builtin_exp2f(mrow - mnew);
        float psum = 0.f;
        f16x4 pf[4];
        #pragma unroll
        for (int mi = 0; mi < 4; ++mi) {
            #pragma unroll
            for (int r = 0; r < 4; ++r) {
                float pv = __builtin_exp2f(sv[mi][r] - mnew);
                psum += pv;
                pf[mi][r] = (_Float16)pv;
            }
        }
        psum += __shfl_xor(psum, 16);
        psum += __shfl_xor(psum, 32);
        lsum = lsum * corr + psum;
        mrow = mnew;
        O0 *= corr; O1 *= corr; O2 *= corr; O3 *= corr;
        #pragma unroll
        for (int mi = 0; mi < 4; ++mi) {
            O0 = __builtin_amdgcn_mfma_f32_16x16x16f16(vv[0][mi], pf[mi], O0, 0, 0, 0);
            O1 = __builtin_amdgcn_mfma_f32_16x16x16f16(vv[1][mi], pf[mi], O1, 0, 0, 0);
            O2 = __builtin_amdgcn_mfma_f32_16x16x16f16(vv[2][mi], pf[mi], O2, 0, 0, 0);
            O3 = __builtin_amdgcn_mfma_f32_16x16x16f16(vv[3][mi], pf[mi], O3, 0, 0, 0);
        }
    }
    int u = ((g * 32 + nt4 * 4 + w) << 3) + s;
    size_t ob = (size_t)(u * 16 + t) * 64;
    *(f32x4*)(Opart + ob + q*4)      = O0;
    *(f32x4*)(Opart + ob + 16 + q*4) = O1;
    *(f32x4*)(Opart + ob + 32 + q*4) = O2;
    *(f32x4*)(Opart + ob + 48 + q*4) = O3;
    if (q == 0) { Mpart[u*16 + t] = mrow; Lpart[u*16 + t] = lsum; }
#undef LOADC
#undef WRITEC
}

// ---------------- combine 8 split-M partials, normalize, + Wv_b ----------------
__global__ __launch_bounds__(256) void mega_combine(
    const float* __restrict__ Opart, const float* __restrict__ Mpart,
    const float* __restrict__ Lpart, const float* __restrict__ Wv_b,
    float* __restrict__ outp)
{
    int idx = blockIdx.x * 256 + threadIdx.x;
    int n = idx >> 10, col = idx & 1023;
    int g = col >> 6, d = col & 63;
    int nt = n >> 4, t = n & 15;
    int u0 = ((g * 32 + nt) << 3);
    float ms[8];
    #pragma unroll
    for (int s = 0; s < 8; ++s) ms[s] = Mpart[(u0 + s) * 16 + t];
    float M = ms[0];
    #pragma unroll
    for (int s = 1; s < 8; ++s) M = fmaxf(M, ms[s]);
    float accO = 0.f, accL = 0.f;
    #pragma unroll
    for (int s = 0; s < 8; ++s) {
        float wgt = __builtin_exp2f(ms[s] - M);
        accO += wgt * Opart[(size_t)((u0 + s) * 16 + t) * 64 + d];
        accL += wgt * Lpart[(u0 + s) * 16 + t];
    }
    outp[idx] = accO / accL + Wv_b[col];
}

extern "C" void kernel_launch(void* const* d_in, const int* in_sizes, int n_in,
                              void* d_out, int out_size, void* d_ws, size_t ws_size,
                              hipStream_t stream)
{
    const float* bbox     = (const float*)d_in[0];
    const float* ref_bbox = (const float*)d_in[1];
    const float* roi_feat = (const float*)d_in[2];
    const float* ref_feat = (const float*)d_in[3];
    const float* Wg_w = (const float*)d_in[4];
    const float* Wg_b = (const float*)d_in[5];
    const float* Wq_w = (const float*)d_in[6];
    const float* Wq_b = (const float*)d_in[7];
    const float* Wk_w = (const float*)d_in[8];
    const float* Wk_b = (const float*)d_in[9];
    const float* Wv_w = (const float*)d_in[10];
    const float* Wv_b = (const float*)d_in[11];
    const float* uvec = (const float*)d_in[12];
    float* outp = (float*)d_out;
    char* ws = (char*)d_ws;

    // prior [16][512][2048] f16 occupies [0,32M) and overlays the f16 input copies,
    // which are dead after mega_gemm (prior is written after gemm completes).
    _Float16* prior = (_Float16*)ws;
    _Float16* roi_h = (_Float16*)(ws + 0);
    _Float16* ref_h = (_Float16*)(ws + (1ull<<20));
    _Float16* wq_h  = (_Float16*)(ws + (5ull<<20));
    _Float16* wk_h  = (_Float16*)(ws + (7ull<<20));
    _Float16* wv_h  = (_Float16*)(ws + (9ull<<20));
    size_t b2 = 32ull<<20;
    _Float16* wg_h  = (_Float16*)(ws + b2);
    float* qbias    = (float*)(ws + b2 + 4096);
    float* roig     = (float*)(ws + b2 + 8192);
    float* refg     = (float*)(ws + b2 + 24576);
    _Float16* Qh    = (_Float16*)(ws + b2 + 65536);
    _Float16* Kh    = (_Float16*)(ws + b2 + 65536 + (1ull<<20));
    _Float16* Vth   = (_Float16*)(ws + b2 + 65536 + (5ull<<20));
    float* Opart    = (float*)(ws + b2 + 65536 + (9ull<<20));
    float* Mpart    = (float*)(ws + b2 + 65536 + (25ull<<20));
    float* Lpart    = (float*)(ws + b2 + 65536 + (25ull<<20) + 262144);

    mega_prep<<<5644, 256, 0, stream>>>(bbox, ref_bbox, roi_feat, ref_feat,
        Wg_w, Wq_w, Wk_w, Wv_w, Wq_b, uvec,
        roi_h, ref_h, wq_h, wk_h, wv_h, wg_h, qbias, roig, refg);
    mega_gemm<<<576, 256, 0, stream>>>(roi_h, ref_h, wq_h, wk_h, wv_h,
        qbias, Wk_b, Qh, Kh, Vth);
    mega_prior<<<1024, 256, 0, stream>>>(wg_h, Wg_b, roig, refg, prior);
    mega_attn<<<1024, 256, 0, stream>>>(Qh, Kh, Vth, prior, Opart, Mpart, Lpart);
    mega_combine<<<2048, 256, 0, stream>>>(Opart, Mpart, Lpart, Wv_b, outp);
}

// Round 4
// 149.786 us; speedup vs baseline: 1.3024x; 1.0809x over previous
//
#include <hip/hip_runtime.h>
#include <stdint.h>

typedef float f32x4 __attribute__((ext_vector_type(4)));
typedef _Float16 f16x8 __attribute__((ext_vector_type(8)));
typedef _Float16 f16x4 __attribute__((ext_vector_type(4)));
typedef int int4v __attribute__((ext_vector_type(4)));

#define LOG2E 1.44269504088896340736f

// global -> LDS direct copy, 16B per lane, wave-uniform LDS base (guide §5)
__device__ __forceinline__ void gload_lds16(const void* g, void* l) {
    auto gp = reinterpret_cast<const uint32_t __attribute__((address_space(1)))*>(
        reinterpret_cast<uintptr_t>(g));
    auto lp = reinterpret_cast<uint32_t __attribute__((address_space(3)))*>(
        reinterpret_cast<uintptr_t>(l));
    __builtin_amdgcn_global_load_lds(gp, lp, 16, 0, 0);
}

// ---------------- prep: f32->f16 converts, qbias=Wq_b+u, bbox geometry ----------------
__global__ __launch_bounds__(256) void mega_prep(
    const float* __restrict__ bbox, const float* __restrict__ ref_bbox,
    const float* __restrict__ roi_feat, const float* __restrict__ ref_feat,
    const float* __restrict__ Wg_w, const float* __restrict__ Wq_w,
    const float* __restrict__ Wk_w, const float* __restrict__ Wv_w,
    const float* __restrict__ Wq_b, const float* __restrict__ uvec,
    _Float16* __restrict__ roi_h, _Float16* __restrict__ ref_h,
    _Float16* __restrict__ wq_h, _Float16* __restrict__ wk_h,
    _Float16* __restrict__ wv_h, _Float16* __restrict__ wg_h,
    float* __restrict__ qbias, float* __restrict__ roig, float* __restrict__ refg)
{
    int idx = blockIdx.x * 256 + threadIdx.x;
    if (idx < 1442048) {
        const float* src; _Float16* dst; int off;
        if (idx < 131072)       { src = roi_feat; dst = roi_h; off = idx; }
        else if (idx < 655360)  { src = ref_feat; dst = ref_h; off = idx - 131072; }
        else if (idx < 917504)  { src = Wq_w;     dst = wq_h;  off = idx - 655360; }
        else if (idx < 1179648) { src = Wk_w;     dst = wk_h;  off = idx - 917504; }
        else if (idx < 1441792) { src = Wv_w;     dst = wv_h;  off = idx - 1179648; }
        else                    { src = Wg_w;     dst = wg_h;  off = idx - 1441792; }
        f32x4 v = *(const f32x4*)(src + (size_t)off * 4);
        f16x4 o;
        o[0] = (_Float16)v[0]; o[1] = (_Float16)v[1];
        o[2] = (_Float16)v[2]; o[3] = (_Float16)v[3];
        *(f16x4*)(dst + (size_t)off * 4) = o;
    } else if (idx < 1442304) {
        int off = idx - 1442048;
        f32x4 a = *(const f32x4*)(Wq_b + off * 4);
        f32x4 b = *(const f32x4*)(uvec + off * 4);
        f32x4 r = a + b;
        *(f32x4*)(qbias + off * 4) = r;
    } else if (idx < 1442816) {
        int n = idx - 1442304;
        f32x4 bb = *(const f32x4*)(bbox + n * 4);
        float w = bb[2] - bb[0] + 1.0f, h = bb[3] - bb[1] + 1.0f;
        f32x4 o1 = {0.5f*(bb[0]+bb[2]), 0.5f*(bb[1]+bb[3]), 1.0f/w, 1.0f/h};
        f32x4 o2 = {__logf(w), __logf(h), 0.f, 0.f};
        *(f32x4*)(roig + n*8) = o1;
        *(f32x4*)(roig + n*8 + 4) = o2;
    } else if (idx < 1444864) {
        int m = idx - 1442816;
        f32x4 bb = *(const f32x4*)(ref_bbox + m * 4);
        float w = bb[2] - bb[0] + 1.0f, h = bb[3] - bb[1] + 1.0f;
        f32x4 o = {0.5f*(bb[0]+bb[2]), 0.5f*(bb[1]+bb[3]), __logf(w), __logf(h)};
        *(f32x4*)(refg + m*4) = o;
    }
}

// ---------------- batched QKV GEMM: C = A*B^T (+bias)*scale ----------------
// 64x128 tile, BK=64, double-buffered LDS, stage-early 2-phase pipeline,
// XOR-swizzled LDS (swizzle applied on global SOURCE; linear gload_lds dest).
// b<64:  Q = roi@Wq^T, scaled 0.125*log2e, bias=Wq_b+u -> Qg [16][512][64]  (g-blocked)
// b<320: K = ref@Wk^T + Wk_b                           -> Kg [16][2048][64] (g-blocked)
// else:  V = ref@Wv'^T                                  -> Vth [1024][2048]  (transposed)
__global__ __launch_bounds__(256) void mega_gemm(
    const _Float16* __restrict__ roi_h, const _Float16* __restrict__ ref_h,
    const _Float16* __restrict__ wq_h, const _Float16* __restrict__ wk_h,
    const _Float16* __restrict__ wv_h, const float* __restrict__ qbias,
    const float* __restrict__ Wk_b,
    _Float16* __restrict__ Qg, _Float16* __restrict__ Kg, _Float16* __restrict__ Vth)
{
    __shared__ __align__(16) _Float16 As[2][64 * 64];    // 2 x 8 KB
    __shared__ __align__(16) _Float16 Bs[2][128 * 64];   // 2 x 16 KB

    int b = blockIdx.x;
    const _Float16 *A, *B;
    const float* bias;
    _Float16* out;
    int tm, tn, mode, MR; float scale;
    if (b < 64)       { A = roi_h; B = wq_h; bias = qbias; out = Qg;  tm = b >> 3;        tn = b & 7;       mode = 0; MR = 512;  scale = 0.125f * LOG2E; }
    else if (b < 320) { A = ref_h; B = wk_h; bias = Wk_b;  out = Kg;  tm = (b-64) >> 3;   tn = (b-64) & 7;  mode = 0; MR = 2048; scale = 1.f; }
    else              { A = ref_h; B = wv_h; bias = nullptr; out = Vth; tm = (b-320) >> 3; tn = (b-320) & 7; mode = 1; MR = 2048; scale = 1.f; }

    int tid = threadIdx.x;
    int w = tid >> 6, l = tid & 63, q = l >> 4, t = l & 15;
    int wm = w >> 1, wn = w & 1;
    int m0 = tm * 64, n0 = tn * 128;

    // staging mapping: row r (+32i), 16B chunk c8; swizzle on global source
    int r = tid >> 3, c8 = tid & 7;
    int swz = (c8 * 16) ^ ((r & 7) << 4);
    const char* gA = (const char*)A + (size_t)(m0 + r) * 2048 + swz;
    const char* gB = (const char*)B + (size_t)(n0 + r) * 2048 + swz;
    char* lA = (char*)&As[0][0] + (w * 8) * 128;   // wave-uniform base
    char* lB = (char*)&Bs[0][0] + (w * 8) * 128;

#define GSTAGE(bufi, kt) { \
    size_t ko = (size_t)(kt) * 128; \
    gload_lds16(gA + ko,               lA + (bufi)*8192); \
    gload_lds16(gA + ko + 32*2048,     lA + (bufi)*8192 + 32*128); \
    gload_lds16(gB + ko,               lB + (bufi)*16384); \
    gload_lds16(gB + ko + 32*2048,     lB + (bufi)*16384 + 32*128); \
    gload_lds16(gB + ko + 64*2048,     lB + (bufi)*16384 + 64*128); \
    gload_lds16(gB + ko + 96*2048,     lB + (bufi)*16384 + 96*128); }

    f32x4 acc[2][4];
    #pragma unroll
    for (int i = 0; i < 2; ++i)
        #pragma unroll
        for (int j = 0; j < 4; ++j)
            acc[i][j] = (f32x4){0.f, 0.f, 0.f, 0.f};

    GSTAGE(0, 0);
    __syncthreads();

    for (int kt = 0; kt < 16; ++kt) {
        int cur = kt & 1;
        if (kt < 15) GSTAGE(cur ^ 1, kt + 1);   // loads fly under compute

        const char* cA = (const char*)&As[0][0] + cur * 8192;
        const char* cB = (const char*)&Bs[0][0] + cur * 16384;
        f16x8 af[2][2], bf[2][4];
        #pragma unroll
        for (int mi = 0; mi < 2; ++mi) {
            int row = wm * 32 + mi * 16 + t;
            int sx = (row & 7) << 4;
            #pragma unroll
            for (int ks = 0; ks < 2; ++ks)
                af[ks][mi] = *(const f16x8*)(cA + row * 128 + ((ks * 64 + q * 16) ^ sx));
        }
        #pragma unroll
        for (int ni = 0; ni < 4; ++ni) {
            int row = wn * 64 + ni * 16 + t;
            int sx = (row & 7) << 4;
            #pragma unroll
            for (int ks = 0; ks < 2; ++ks)
                bf[ks][ni] = *(const f16x8*)(cB + row * 128 + ((ks * 64 + q * 16) ^ sx));
        }
        #pragma unroll
        for (int ks = 0; ks < 2; ++ks)
            #pragma unroll
            for (int mi = 0; mi < 2; ++mi)
                #pragma unroll
                for (int ni = 0; ni < 4; ++ni)
                    acc[mi][ni] = __builtin_amdgcn_mfma_f32_16x16x32_f16(af[ks][mi], bf[ks][ni], acc[mi][ni], 0, 0, 0);
        __syncthreads();   // drains stage loads; guards buffer reuse
    }
#undef GSTAGE

    #pragma unroll
    for (int mi = 0; mi < 2; ++mi) {
        #pragma unroll
        for (int ni = 0; ni < 4; ++ni) {
            int col  = n0 + wn*64 + ni*16 + t;
            int row0 = m0 + wm*32 + mi*16 + q*4;
            f32x4 a = acc[mi][ni];
            if (mode == 0) {
                // g-blocked: out[g][row][d], g = col>>6, d = col&63
                float bb = bias[col];
                _Float16* op = out + ((size_t)(col >> 6) * MR + row0) * 64 + (col & 63);
                #pragma unroll
                for (int rr = 0; rr < 4; ++rr)
                    op[(size_t)rr * 64] = (_Float16)((a[rr] + bb) * scale);
            } else {
                f16x4 pk;
                pk[0] = (_Float16)a[0]; pk[1] = (_Float16)a[1];
                pk[2] = (_Float16)a[2]; pk[3] = (_Float16)a[3];
                *(f16x4*)(out + (size_t)col * 2048 + row0) = pk;
            }
        }
    }
}

// ---------------- position prior: relu(Wg @ emb + Wg_b), via MFMA ----------------
// output layout [g][n][m] f16: prior[g*512*2048 + n*2048 + m]
__global__ __launch_bounds__(256) void mega_prior(
    const _Float16* __restrict__ wg_h, const float* __restrict__ Wg_b,
    const float* __restrict__ roig, const float* __restrict__ refg,
    _Float16* __restrict__ prior)
{
    int tid = threadIdx.x;
    int w = tid >> 6, l = tid & 63, q = l >> 4, p = l & 15;
    int n = blockIdx.x >> 1, half = blockIdx.x & 1;

    f16x8 wa0 = *(const f16x8*)(wg_h + p*64 + q*8);
    f16x8 wa1 = *(const f16x8*)(wg_h + p*64 + 32 + q*8);
    f32x4 wb = *(const f32x4*)(Wg_b + q*4);

    f32x4 rg1 = *(const f32x4*)(roig + n*8);
    f32x4 rg2 = *(const f32x4*)(roig + n*8 + 4);

    float cf[8];
    #pragma unroll
    for (int f = 0; f < 8; ++f)
        cf[f] = 15.9154943091895336f * __builtin_exp2f(-1.24572303558276059f * (float)f);

    float coff = (q & 1) ? 0.25f : 0.0f;   // cos(x) = sin(x + 1/4 rev)
    bool isX = (q < 2);

    int mstart = half * 1024 + w * 256;
    for (int it = 0; it < 16; ++it) {
        int m = mstart + it * 16 + p;
        f32x4 rg = *(const f32x4*)(refg + m * 4);
        float posA = isX ? __logf(fabsf(rg1[0] - rg[0]) * rg1[2] + 1e-3f)
                         : __logf(fabsf(rg1[1] - rg[1]) * rg1[3] + 1e-3f);
        float posB = isX ? (rg2[0] - rg[2]) : (rg2[1] - rg[3]);
        f16x8 e0, e1;
        #pragma unroll
        for (int f = 0; f < 8; ++f) {
            float a0 = posA * cf[f] + coff; a0 -= floorf(a0);
            float a1 = posB * cf[f] + coff; a1 -= floorf(a1);
            e0[f] = (_Float16)__builtin_amdgcn_sinf(a0);
            e1[f] = (_Float16)__builtin_amdgcn_sinf(a1);
        }
        f32x4 acc = wb;
        acc = __builtin_amdgcn_mfma_f32_16x16x32_f16(wa0, e0, acc, 0, 0, 0);
        acc = __builtin_amdgcn_mfma_f32_16x16x32_f16(wa1, e1, acc, 0, 0, 0);
        _Float16* pp = prior + (size_t)n * 2048 + m;
        #pragma unroll
        for (int r = 0; r < 4; ++r)
            pp[(size_t)(q*4 + r) * 1048576] = (_Float16)fmaxf(acc[r], 0.f);
    }
}

// ---------------- flash attention, LDS-staged, double-buffered ----------------
// block = 4 waves = (g, 64 n rows, 256-m span). Per 64-m chunk: stage
// K[64][64], V^T[64][64], prior[64][64] into LDS (coalesced, XOR-swizzled).
// Double-buffer: chunk c+1's global loads issued BEFORE compute of chunk c,
// ds-writes after; one barrier per chunk.
#define SWZ(row, cb) ((cb) ^ (((row) & 7) << 4))

__device__ __forceinline__ f16x8 ld128s(const _Float16* base, int row, int cb) {
    return *(const f16x8*)((const char*)base + row * 128 + SWZ(row, cb));
}
__device__ __forceinline__ f16x4 ld64s(const _Float16* base, int row, int cb) {
    return *(const f16x4*)((const char*)base + row * 128 + SWZ(row, cb));
}

__global__ __launch_bounds__(256, 3) void mega_attn(
    const _Float16* __restrict__ Qg, const _Float16* __restrict__ Kg,
    const _Float16* __restrict__ Vth, const _Float16* __restrict__ prior,
    _Float16* __restrict__ Opart, float* __restrict__ Mpart, float* __restrict__ Lpart)
{
    __shared__ __align__(16) _Float16 Kl[2][4096];
    __shared__ __align__(16) _Float16 Vl[2][4096];
    __shared__ __align__(16) _Float16 Pl[2][4096];

    int bid = blockIdx.x;
    int g = bid >> 6, nt4 = (bid >> 3) & 7, s = bid & 7;
    int tid = threadIdx.x;
    int w = tid >> 6, l = tid & 63, q = l >> 4, t = l & 15;
    int n0 = nt4 * 64, m0 = s * 256;

    int n = n0 + w * 16 + t;
    const _Float16* Qrow = Qg + ((size_t)g * 512 + n) * 64;
    f16x8 qf0 = *(const f16x8*)(Qrow + q * 8);
    f16x8 qf1 = *(const f16x8*)(Qrow + 32 + q * 8);

    // staging lane mapping: row r = tid/8 (+32), 16B chunk c8 = tid%8
    int r_lo = tid >> 3, c8 = tid & 7;
    const char* gK = (const char*)(Kg + ((size_t)g * 2048 + m0) * 64);
    const char* gV = (const char*)(Vth + (size_t)g * 64 * 2048 + m0);
    const char* gP = (const char*)(prior + ((size_t)g * 512 + n0) * 2048 + m0);

    int4v kr0, kr1, vr0, vr1, pq0, pq1;
#define LOADC(c) { \
    kr0 = *(const int4v*)(gK + (c)*8192 + r_lo*128 + c8*16); \
    kr1 = *(const int4v*)(gK + (c)*8192 + (r_lo+32)*128 + c8*16); \
    vr0 = *(const int4v*)(gV + (c)*128 + (size_t)r_lo*4096 + c8*16); \
    vr1 = *(const int4v*)(gV + (c)*128 + (size_t)(r_lo+32)*4096 + c8*16); \
    pq0 = *(const int4v*)(gP + (c)*128 + (size_t)r_lo*4096 + c8*16); \
    pq1 = *(const int4v*)(gP + (c)*128 + (size_t)(r_lo+32)*4096 + c8*16); }
#define WRITEC(bufi) { \
    int cb = c8 * 16, sw = SWZ(r_lo, cb); \
    *(int4v*)((char*)&Kl[bufi][0] + r_lo*128 + sw) = kr0; \
    *(int4v*)((char*)&Kl[bufi][0] + (r_lo+32)*128 + sw) = kr1; \
    *(int4v*)((char*)&Vl[bufi][0] + r_lo*128 + sw) = vr0; \
    *(int4v*)((char*)&Vl[bufi][0] + (r_lo+32)*128 + sw) = vr1; \
    *(int4v*)((char*)&Pl[bufi][0] + r_lo*128 + sw) = pq0; \
    *(int4v*)((char*)&Pl[bufi][0] + (r_lo+32)*128 + sw) = pq1; }

    float mrow = -INFINITY, lsum = 0.f;
    f32x4 O0 = {0,0,0,0}, O1 = {0,0,0,0}, O2 = {0,0,0,0}, O3 = {0,0,0,0};

    LOADC(0);
    WRITEC(0);
    __syncthreads();

    for (int c = 0; c < 4; ++c) {
        int cur = c & 1;
        if (c < 3) LOADC(c + 1);   // issue early; lands during compute (T14)

        const _Float16* Kb_l = &Kl[cur][0];
        const _Float16* Vb_l = &Vl[cur][0];
        const _Float16* Pb_l = &Pl[cur][0];

        // prior fragments
        f16x4 pr[4];
        #pragma unroll
        for (int mi = 0; mi < 4; ++mi)
            pr[mi] = ld64s(Pb_l, w * 16 + t, mi * 32 + q * 8);
        // QK^T with C=0
        f32x4 sv[4];
        __builtin_amdgcn_s_setprio(1);
        #pragma unroll
        for (int mi = 0; mi < 4; ++mi) {
            f16x8 k0 = ld128s(Kb_l, mi * 16 + t, q * 16);
            f16x8 k1 = ld128s(Kb_l, mi * 16 + t, 64 + q * 16);
            f32x4 z = {0, 0, 0, 0};
            z = __builtin_amdgcn_mfma_f32_16x16x32_f16(k0, qf0, z, 0, 0, 0);
            z = __builtin_amdgcn_mfma_f32_16x16x32_f16(k1, qf1, z, 0, 0, 0);
            sv[mi] = z;
        }
        __builtin_amdgcn_s_setprio(0);
        #pragma unroll
        for (int mi = 0; mi < 4; ++mi)
            #pragma unroll
            for (int r = 0; r < 4; ++r)
                sv[mi][r] += __log2f((float)pr[mi][r] + 1e-6f);
        // V fragments
        f16x4 vv[4][4];
        #pragma unroll
        for (int i = 0; i < 4; ++i)
            #pragma unroll
            for (int mi = 0; mi < 4; ++mi)
                vv[i][mi] = ld64s(Vb_l, i * 16 + t, mi * 32 + q * 8);
        // online softmax (log2 domain)
        float cmax = -INFINITY;
        #pragma unroll
        for (int mi = 0; mi < 4; ++mi)
            #pragma unroll
            for (int r = 0; r < 4; ++r)
                cmax = fmaxf(cmax, sv[mi][r]);
        cmax = fmaxf(cmax, __shfl_xor(cmax, 16));
        cmax = fmaxf(cmax, __shfl_xor(cmax, 32));
        float mnew = fmaxf(mrow, cmax);
        float corr = __builtin_exp2f(mrow - mnew);
        float psum = 0.f;
        f16x4 pf[4];
        #pragma unroll
        for (int mi = 0; mi < 4; ++mi) {
            #pragma unroll
            for (int r = 0; r < 4; ++r) {
                float pv = __builtin_exp2f(sv[mi][r] - mnew);
                psum += pv;
                pf[mi][r] = (_Float16)pv;
            }
        }
        psum += __shfl_xor(psum, 16);
        psum += __shfl_xor(psum, 32);
        lsum = lsum * corr + psum;
        mrow = mnew;
        O0 *= corr; O1 *= corr; O2 *= corr; O3 *= corr;
        __builtin_amdgcn_s_setprio(1);
        #pragma unroll
        for (int mi = 0; mi < 4; ++mi) {
            O0 = __builtin_amdgcn_mfma_f32_16x16x16f16(vv[0][mi], pf[mi], O0, 0, 0, 0);
            O1 = __builtin_amdgcn_mfma_f32_16x16x16f16(vv[1][mi], pf[mi], O1, 0, 0, 0);
            O2 = __builtin_amdgcn_mfma_f32_16x16x16f16(vv[2][mi], pf[mi], O2, 0, 0, 0);
            O3 = __builtin_amdgcn_mfma_f32_16x16x16f16(vv[3][mi], pf[mi], O3, 0, 0, 0);
        }
        __builtin_amdgcn_s_setprio(0);

        if (c < 3) WRITEC(cur ^ 1);   // ds-write next chunk (waits its loads)
        __syncthreads();
    }

    int u = ((g * 32 + nt4 * 4 + w) << 3) + s;
    size_t ob = (size_t)(u * 16 + t) * 64;
    f16x4 ph;
#define PK(O) { ph[0]=(_Float16)O[0]; ph[1]=(_Float16)O[1]; ph[2]=(_Float16)O[2]; ph[3]=(_Float16)O[3]; }
    PK(O0) *(f16x4*)(Opart + ob + q*4)      = ph;
    PK(O1) *(f16x4*)(Opart + ob + 16 + q*4) = ph;
    PK(O2) *(f16x4*)(Opart + ob + 32 + q*4) = ph;
    PK(O3) *(f16x4*)(Opart + ob + 48 + q*4) = ph;
#undef PK
    if (q == 0) { Mpart[u*16 + t] = mrow; Lpart[u*16 + t] = lsum; }
#undef LOADC
#undef WRITEC
}

// ---------------- combine 8 split-M partials, normalize, + Wv_b ----------------
__global__ __launch_bounds__(256) void mega_combine(
    const _Float16* __restrict__ Opart, const float* __restrict__ Mpart,
    const float* __restrict__ Lpart, const float* __restrict__ Wv_b,
    float* __restrict__ outp)
{
    int idx = blockIdx.x * 256 + threadIdx.x;
    int n = idx >> 10, col = idx & 1023;
    int g = col >> 6, d = col & 63;
    int nt = n >> 4, t = n & 15;
    int u0 = ((g * 32 + nt) << 3);
    float ms[8];
    #pragma unroll
    for (int s = 0; s < 8; ++s) ms[s] = Mpart[(u0 + s) * 16 + t];
    float M = ms[0];
    #pragma unroll
    for (int s = 1; s < 8; ++s) M = fmaxf(M, ms[s]);
    float accO = 0.f, accL = 0.f;
    #pragma unroll
    for (int s = 0; s < 8; ++s) {
        float wgt = __builtin_exp2f(ms[s] - M);
        accO += wgt * (float)Opart[(size_t)((u0 + s) * 16 + t) * 64 + d];
        accL += wgt * Lpart[(u0 + s) * 16 + t];
    }
    outp[idx] = accO / accL + Wv_b[col];
}

extern "C" void kernel_launch(void* const* d_in, const int* in_sizes, int n_in,
                              void* d_out, int out_size, void* d_ws, size_t ws_size,
                              hipStream_t stream)
{
    const float* bbox     = (const float*)d_in[0];
    const float* ref_bbox = (const float*)d_in[1];
    const float* roi_feat = (const float*)d_in[2];
    const float* ref_feat = (const float*)d_in[3];
    const float* Wg_w = (const float*)d_in[4];
    const float* Wg_b = (const float*)d_in[5];
    const float* Wq_w = (const float*)d_in[6];
    const float* Wq_b = (const float*)d_in[7];
    const float* Wk_w = (const float*)d_in[8];
    const float* Wk_b = (const float*)d_in[9];
    const float* Wv_w = (const float*)d_in[10];
    const float* Wv_b = (const float*)d_in[11];
    const float* uvec = (const float*)d_in[12];
    float* outp = (float*)d_out;
    char* ws = (char*)d_ws;

    // prior [16][512][2048] f16 occupies [0,32M) and overlays the f16 input copies,
    // which are dead after mega_gemm (prior is written after gemm completes).
    _Float16* prior = (_Float16*)ws;
    _Float16* roi_h = (_Float16*)(ws + 0);
    _Float16* ref_h = (_Float16*)(ws + (1ull<<20));
    _Float16* wq_h  = (_Float16*)(ws + (5ull<<20));
    _Float16* wk_h  = (_Float16*)(ws + (7ull<<20));
    _Float16* wv_h  = (_Float16*)(ws + (9ull<<20));
    size_t b2 = 32ull<<20;
    _Float16* wg_h  = (_Float16*)(ws + b2);
    float* qbias    = (float*)(ws + b2 + 4096);
    float* roig     = (float*)(ws + b2 + 8192);
    float* refg     = (float*)(ws + b2 + 24576);
    _Float16* Qh    = (_Float16*)(ws + b2 + 65536);
    _Float16* Kh    = (_Float16*)(ws + b2 + 65536 + (1ull<<20));
    _Float16* Vth   = (_Float16*)(ws + b2 + 65536 + (5ull<<20));
    _Float16* Opart = (_Float16*)(ws + b2 + 65536 + (9ull<<20));
    float* Mpart    = (float*)(ws + b2 + 65536 + (25ull<<20));
    float* Lpart    = (float*)(ws + b2 + 65536 + (25ull<<20) + 262144);

    mega_prep<<<5644, 256, 0, stream>>>(bbox, ref_bbox, roi_feat, ref_feat,
        Wg_w, Wq_w, Wk_w, Wv_w, Wq_b, uvec,
        roi_h, ref_h, wq_h, wk_h, wv_h, wg_h, qbias, roig, refg);
    mega_gemm<<<576, 256, 0, stream>>>(roi_h, ref_h, wq_h, wk_h, wv_h,
        qbias, Wk_b, Qh, Kh, Vth);
    mega_prior<<<1024, 256, 0, stream>>>(wg_h, Wg_b, roig, refg, prior);
    mega_attn<<<1024, 256, 0, stream>>>(Qh, Kh, Vth, prior, Opart, Mpart, Lpart);
    mega_combine<<<2048, 256, 0, stream>>>(Opart, Mpart, Lpart, Wv_b, outp);
}

// Round 5
// 146.864 us; speedup vs baseline: 1.3283x; 1.0199x over previous
//
#include <hip/hip_runtime.h>
#include <stdint.h>

typedef float f32x4 __attribute__((ext_vector_type(4)));
typedef _Float16 f16x8 __attribute__((ext_vector_type(8)));
typedef _Float16 f16x4 __attribute__((ext_vector_type(4)));
typedef int int4v __attribute__((ext_vector_type(4)));

#define LOG2E 1.44269504088896340736f

// global -> LDS direct copy, 16B per lane, wave-uniform LDS base (guide §5)
__device__ __forceinline__ void gload_lds16(const void* g, void* l) {
    auto gp = reinterpret_cast<const uint32_t __attribute__((address_space(1)))*>(
        reinterpret_cast<uintptr_t>(g));
    auto lp = reinterpret_cast<uint32_t __attribute__((address_space(3)))*>(
        reinterpret_cast<uintptr_t>(l));
    __builtin_amdgcn_global_load_lds(gp, lp, 16, 0, 0);
}

// ---------------- prep: pure f32->f16 converts (5 arrays) ----------------
__global__ __launch_bounds__(256) void mega_prep(
    const float* __restrict__ roi_feat, const float* __restrict__ ref_feat,
    const float* __restrict__ Wg_w, const float* __restrict__ Wq_w,
    const float* __restrict__ Wk_w, const float* __restrict__ Wv_w,
    _Float16* __restrict__ roi_h, _Float16* __restrict__ ref_h,
    _Float16* __restrict__ wq_h, _Float16* __restrict__ wk_h,
    _Float16* __restrict__ wv_h, _Float16* __restrict__ wg_h)
{
    int idx = blockIdx.x * 256 + threadIdx.x;   // grid 5633*256 == 1442048 exactly
    const float* src; _Float16* dst; int off;
    if (idx < 131072)       { src = roi_feat; dst = roi_h; off = idx; }
    else if (idx < 655360)  { src = ref_feat; dst = ref_h; off = idx - 131072; }
    else if (idx < 917504)  { src = Wq_w;     dst = wq_h;  off = idx - 655360; }
    else if (idx < 1179648) { src = Wk_w;     dst = wk_h;  off = idx - 917504; }
    else if (idx < 1441792) { src = Wv_w;     dst = wv_h;  off = idx - 1179648; }
    else                    { src = Wg_w;     dst = wg_h;  off = idx - 1441792; }
    f32x4 v = *(const f32x4*)(src + (size_t)off * 4);
    f16x4 o;
    o[0] = (_Float16)v[0]; o[1] = (_Float16)v[1];
    o[2] = (_Float16)v[2]; o[3] = (_Float16)v[3];
    *(f16x4*)(dst + (size_t)off * 4) = o;
}

// ---------------- merged GEMM (64x64 tiles) + position prior ----------------
// b<128:   Q = roi@Wq^T (+Wq_b+u)*0.125*log2e -> Qg [16][512][64]  (g-blocked)
// b<640:   K = ref@Wk^T + Wk_b                -> Kg [16][2048][64] (g-blocked)
// b<1152:  V = ref@Wv'^T                      -> Vth [1024][2048]  (transposed)
// b>=1152: prior role: relu(Wg@emb + Wg_b) -> prior [16][512][2048] f16
__global__ __launch_bounds__(256, 4) void mega_gp(
    const _Float16* __restrict__ roi_h, const _Float16* __restrict__ ref_h,
    const _Float16* __restrict__ wq_h, const _Float16* __restrict__ wk_h,
    const _Float16* __restrict__ wv_h, const _Float16* __restrict__ wg_h,
    const float* __restrict__ Wq_b, const float* __restrict__ uvec,
    const float* __restrict__ Wk_b, const float* __restrict__ Wg_b,
    const float* __restrict__ bbox, const float* __restrict__ ref_bbox,
    _Float16* __restrict__ Qg, _Float16* __restrict__ Kg, _Float16* __restrict__ Vth,
    _Float16* __restrict__ prior)
{
    __shared__ __align__(16) _Float16 As[2][4096];   // 2 x 8 KB
    __shared__ __align__(16) _Float16 Bs[2][4096];   // 2 x 8 KB

    int b = blockIdx.x;
    int tid = threadIdx.x;
    int w = tid >> 6, l = tid & 63, q = l >> 4, t = l & 15;

    if (b >= 1152) {
        // ---- position prior role ----
        int pb = b - 1152;
        int p = l & 15;
        int n = pb >> 1, half = pb & 1;

        f16x8 wa0 = *(const f16x8*)(wg_h + p*64 + q*8);
        f16x8 wa1 = *(const f16x8*)(wg_h + p*64 + 32 + q*8);
        f32x4 wb = *(const f32x4*)(Wg_b + q*4);

        // inline roi geometry
        f32x4 bbx = *(const f32x4*)(bbox + n * 4);
        float bw = bbx[2] - bbx[0] + 1.0f, bh = bbx[3] - bbx[1] + 1.0f;
        float cx = 0.5f*(bbx[0]+bbx[2]), cy = 0.5f*(bbx[1]+bbx[3]);
        float invw = 1.0f/bw, invh = 1.0f/bh;
        float lgw = __logf(bw), lgh = __logf(bh);

        float cf[8];
        #pragma unroll
        for (int f = 0; f < 8; ++f)
            cf[f] = 15.9154943091895336f * __builtin_exp2f(-1.24572303558276059f * (float)f);

        float coff = (q & 1) ? 0.25f : 0.0f;   // cos(x) = sin(x + 1/4 rev)
        bool isX = (q < 2);
        float cA  = isX ? cx : cy;
        float invA = isX ? invw : invh;
        float lgA = isX ? lgw : lgh;

        int mstart = half * 1024 + w * 256;
        for (int it = 0; it < 16; ++it) {
            int m = mstart + it * 16 + p;
            f32x4 rb = *(const f32x4*)(ref_bbox + m * 4);
            float cAr = isX ? 0.5f*(rb[0]+rb[2]) : 0.5f*(rb[1]+rb[3]);
            float sAr = isX ? (rb[2]-rb[0]+1.0f) : (rb[3]-rb[1]+1.0f);
            float posA = __logf(fabsf(cA - cAr) * invA + 1e-3f);
            float posB = lgA - __logf(sAr);
            f16x8 e0, e1;
            #pragma unroll
            for (int f = 0; f < 8; ++f) {
                float a0 = posA * cf[f] + coff; a0 -= floorf(a0);
                float a1 = posB * cf[f] + coff; a1 -= floorf(a1);
                e0[f] = (_Float16)__builtin_amdgcn_sinf(a0);
                e1[f] = (_Float16)__builtin_amdgcn_sinf(a1);
            }
            f32x4 acc = wb;
            acc = __builtin_amdgcn_mfma_f32_16x16x32_f16(wa0, e0, acc, 0, 0, 0);
            acc = __builtin_amdgcn_mfma_f32_16x16x32_f16(wa1, e1, acc, 0, 0, 0);
            _Float16* pp = prior + (size_t)n * 2048 + m;
            #pragma unroll
            for (int r = 0; r < 4; ++r)
                pp[(size_t)(q*4 + r) * 1048576] = (_Float16)fmaxf(acc[r], 0.f);
        }
        return;
    }

    // ---- GEMM role: 64x64 tile, BK=64, double-buffered ----
    const _Float16 *A, *B;
    _Float16* out;
    int tm, tn, mode; float scale;
    if (b < 128)      { A = roi_h; B = wq_h; out = Qg;  tm = b >> 4;        tn = b & 15;       mode = 0; scale = 0.125f * LOG2E; }
    else if (b < 640) { A = ref_h; B = wk_h; out = Kg;  tm = (b-128) >> 4;  tn = (b-128) & 15; mode = 1; scale = 1.f; }
    else              { A = ref_h; B = wv_h; out = Vth; tm = (b-640) >> 4;  tn = (b-640) & 15; mode = 2; scale = 1.f; }
    int MR = (b < 128) ? 512 : 2048;

    int wm = w >> 1, wn = w & 1;
    int m0 = tm * 64, n0 = tn * 64;

    // staging: row r_lo (+32), 16B chunk c8; swizzle on global source (rule 21)
    int r_lo = tid >> 3, c8 = tid & 7;
    int swz = (c8 * 16) ^ ((r_lo & 7) << 4);
    const char* gA = (const char*)A + (size_t)(m0 + r_lo) * 2048 + swz;
    const char* gB = (const char*)B + (size_t)(n0 + r_lo) * 2048 + swz;
    char* lA = (char*)&As[0][0] + w * 1024;   // wave-uniform base, 8 rows/wave
    char* lB = (char*)&Bs[0][0] + w * 1024;

#define GSTAGE(bufi, kt) { \
    size_t ko = (size_t)(kt) * 128; \
    gload_lds16(gA + ko,           lA + (bufi)*8192); \
    gload_lds16(gA + ko + 32*2048, lA + (bufi)*8192 + 4096); \
    gload_lds16(gB + ko,           lB + (bufi)*8192); \
    gload_lds16(gB + ko + 32*2048, lB + (bufi)*8192 + 4096); }

    f32x4 acc[2][2];
    #pragma unroll
    for (int i = 0; i < 2; ++i)
        #pragma unroll
        for (int j = 0; j < 2; ++j)
            acc[i][j] = (f32x4){0.f, 0.f, 0.f, 0.f};

    GSTAGE(0, 0);
    __syncthreads();

    for (int kt = 0; kt < 16; ++kt) {
        int cur = kt & 1;
        if (kt < 15) GSTAGE(cur ^ 1, kt + 1);   // next tile's loads fly under compute

        const char* cA = (const char*)&As[0][0] + cur * 8192;
        const char* cB = (const char*)&Bs[0][0] + cur * 8192;
        f16x8 af[2][2], bf[2][2];
        #pragma unroll
        for (int mi = 0; mi < 2; ++mi) {
            int row = wm * 32 + mi * 16 + t;
            int sx = (row & 7) << 4;
            #pragma unroll
            for (int ks = 0; ks < 2; ++ks)
                af[ks][mi] = *(const f16x8*)(cA + row * 128 + ((ks * 64 + q * 16) ^ sx));
        }
        #pragma unroll
        for (int ni = 0; ni < 2; ++ni) {
            int row = wn * 32 + ni * 16 + t;
            int sx = (row & 7) << 4;
            #pragma unroll
            for (int ks = 0; ks < 2; ++ks)
                bf[ks][ni] = *(const f16x8*)(cB + row * 128 + ((ks * 64 + q * 16) ^ sx));
        }
        #pragma unroll
        for (int ks = 0; ks < 2; ++ks)
            #pragma unroll
            for (int mi = 0; mi < 2; ++mi)
                #pragma unroll
                for (int ni = 0; ni < 2; ++ni)
                    acc[mi][ni] = __builtin_amdgcn_mfma_f32_16x16x32_f16(af[ks][mi], bf[ks][ni], acc[mi][ni], 0, 0, 0);
        __syncthreads();   // drains stage loads; guards buffer reuse
    }
#undef GSTAGE

    #pragma unroll
    for (int mi = 0; mi < 2; ++mi) {
        #pragma unroll
        for (int ni = 0; ni < 2; ++ni) {
            int col  = n0 + wn*32 + ni*16 + t;
            int row0 = m0 + wm*32 + mi*16 + q*4;
            f32x4 a = acc[mi][ni];
            if (mode == 2) {
                f16x4 pk;
                pk[0] = (_Float16)a[0]; pk[1] = (_Float16)a[1];
                pk[2] = (_Float16)a[2]; pk[3] = (_Float16)a[3];
                *(f16x4*)(out + (size_t)col * 2048 + row0) = pk;
            } else {
                float bb = (mode == 0) ? (Wq_b[col] + uvec[col]) : Wk_b[col];
                _Float16* op = out + ((size_t)(col >> 6) * MR + row0) * 64 + (col & 63);
                #pragma unroll
                for (int rr = 0; rr < 4; ++rr)
                    op[(size_t)rr * 64] = (_Float16)((a[rr] + bb) * scale);
            }
        }
    }
}

// ---------------- flash attention, LDS-staged, double-buffered ----------------
// block = 4 waves = (g, 64 n rows, 256-m span). Per 64-m chunk: stage
// K[64][64], V^T[64][64], prior[64][64] into LDS (coalesced, XOR-swizzled).
#define SWZ(row, cb) ((cb) ^ (((row) & 7) << 4))

__device__ __forceinline__ f16x8 ld128s(const _Float16* base, int row, int cb) {
    return *(const f16x8*)((const char*)base + row * 128 + SWZ(row, cb));
}
__device__ __forceinline__ f16x4 ld64s(const _Float16* base, int row, int cb) {
    return *(const f16x4*)((const char*)base + row * 128 + SWZ(row, cb));
}

__global__ __launch_bounds__(256, 3) void mega_attn(
    const _Float16* __restrict__ Qg, const _Float16* __restrict__ Kg,
    const _Float16* __restrict__ Vth, const _Float16* __restrict__ prior,
    _Float16* __restrict__ Opart, float* __restrict__ Mpart, float* __restrict__ Lpart)
{
    __shared__ __align__(16) _Float16 Kl[2][4096];
    __shared__ __align__(16) _Float16 Vl[2][4096];
    __shared__ __align__(16) _Float16 Pl[2][4096];

    int bid = blockIdx.x;
    int g = bid >> 6, nt4 = (bid >> 3) & 7, s = bid & 7;
    int tid = threadIdx.x;
    int w = tid >> 6, l = tid & 63, q = l >> 4, t = l & 15;
    int n0 = nt4 * 64, m0 = s * 256;

    int n = n0 + w * 16 + t;
    const _Float16* Qrow = Qg + ((size_t)g * 512 + n) * 64;
    f16x8 qf0 = *(const f16x8*)(Qrow + q * 8);
    f16x8 qf1 = *(const f16x8*)(Qrow + 32 + q * 8);

    int r_lo = tid >> 3, c8 = tid & 7;
    const char* gK = (const char*)(Kg + ((size_t)g * 2048 + m0) * 64);
    const char* gV = (const char*)(Vth + (size_t)g * 64 * 2048 + m0);
    const char* gP = (const char*)(prior + ((size_t)g * 512 + n0) * 2048 + m0);

    int4v kr0, kr1, vr0, vr1, pq0, pq1;
#define LOADC(c) { \
    kr0 = *(const int4v*)(gK + (c)*8192 + r_lo*128 + c8*16); \
    kr1 = *(const int4v*)(gK + (c)*8192 + (r_lo+32)*128 + c8*16); \
    vr0 = *(const int4v*)(gV + (c)*128 + (size_t)r_lo*4096 + c8*16); \
    vr1 = *(const int4v*)(gV + (c)*128 + (size_t)(r_lo+32)*4096 + c8*16); \
    pq0 = *(const int4v*)(gP + (c)*128 + (size_t)r_lo*4096 + c8*16); \
    pq1 = *(const int4v*)(gP + (c)*128 + (size_t)(r_lo+32)*4096 + c8*16); }
#define WRITEC(bufi) { \
    int cb = c8 * 16, sw = SWZ(r_lo, cb); \
    *(int4v*)((char*)&Kl[bufi][0] + r_lo*128 + sw) = kr0; \
    *(int4v*)((char*)&Kl[bufi][0] + (r_lo+32)*128 + sw) = kr1; \
    *(int4v*)((char*)&Vl[bufi][0] + r_lo*128 + sw) = vr0; \
    *(int4v*)((char*)&Vl[bufi][0] + (r_lo+32)*128 + sw) = vr1; \
    *(int4v*)((char*)&Pl[bufi][0] + r_lo*128 + sw) = pq0; \
    *(int4v*)((char*)&Pl[bufi][0] + (r_lo+32)*128 + sw) = pq1; }

    float mrow = -INFINITY, lsum = 0.f;
    f32x4 O0 = {0,0,0,0}, O1 = {0,0,0,0}, O2 = {0,0,0,0}, O3 = {0,0,0,0};

    LOADC(0);
    WRITEC(0);
    __syncthreads();

    for (int c = 0; c < 4; ++c) {
        int cur = c & 1;
        if (c < 3) LOADC(c + 1);   // issue early; lands during compute (T14)

        const _Float16* Kb_l = &Kl[cur][0];
        const _Float16* Vb_l = &Vl[cur][0];
        const _Float16* Pb_l = &Pl[cur][0];

        f16x4 pr[4];
        #pragma unroll
        for (int mi = 0; mi < 4; ++mi)
            pr[mi] = ld64s(Pb_l, w * 16 + t, mi * 32 + q * 8);
        f32x4 sv[4];
        __builtin_amdgcn_s_setprio(1);
        #pragma unroll
        for (int mi = 0; mi < 4; ++mi) {
            f16x8 k0 = ld128s(Kb_l, mi * 16 + t, q * 16);
            f16x8 k1 = ld128s(Kb_l, mi * 16 + t, 64 + q * 16);
            f32x4 z = {0, 0, 0, 0};
            z = __builtin_amdgcn_mfma_f32_16x16x32_f16(k0, qf0, z, 0, 0, 0);
            z = __builtin_amdgcn_mfma_f32_16x16x32_f16(k1, qf1, z, 0, 0, 0);
            sv[mi] = z;
        }
        __builtin_amdgcn_s_setprio(0);
        #pragma unroll
        for (int mi = 0; mi < 4; ++mi)
            #pragma unroll
            for (int r = 0; r < 4; ++r)
                sv[mi][r] += __log2f((float)pr[mi][r] + 1e-6f);
        f16x4 vv[4][4];
        #pragma unroll
        for (int i = 0; i < 4; ++i)
            #pragma unroll
            for (int mi = 0; mi < 4; ++mi)
                vv[i][mi] = ld64s(Vb_l, i * 16 + t, mi * 32 + q * 8);
        float cmax = -INFINITY;
        #pragma unroll
        for (int mi = 0; mi < 4; ++mi)
            #pragma unroll
            for (int r = 0; r < 4; ++r)
                cmax = fmaxf(cmax, sv[mi][r]);
        cmax = fmaxf(cmax, __shfl_xor(cmax, 16));
        cmax = fmaxf(cmax, __shfl_xor(cmax, 32));
        float mnew = fmaxf(mrow, cmax);
        float corr = __builtin_exp2f(mrow - mnew);
        float psum = 0.f;
        f16x4 pf[4];
        #pragma unroll
        for (int mi = 0; mi < 4; ++mi) {
            #pragma unroll
            for (int r = 0; r < 4; ++r) {
                float pv = __builtin_exp2f(sv[mi][r] - mnew);
                psum += pv;
                pf[mi][r] = (_Float16)pv;
            }
        }
        psum += __shfl_xor(psum, 16);
        psum += __shfl_xor(psum, 32);
        lsum = lsum * corr + psum;
        mrow = mnew;
        O0 *= corr; O1 *= corr; O2 *= corr; O3 *= corr;
        __builtin_amdgcn_s_setprio(1);
        #pragma unroll
        for (int mi = 0; mi < 4; ++mi) {
            O0 = __builtin_amdgcn_mfma_f32_16x16x16f16(vv[0][mi], pf[mi], O0, 0, 0, 0);
            O1 = __builtin_amdgcn_mfma_f32_16x16x16f16(vv[1][mi], pf[mi], O1, 0, 0, 0);
            O2 = __builtin_amdgcn_mfma_f32_16x16x16f16(vv[2][mi], pf[mi], O2, 0, 0, 0);
            O3 = __builtin_amdgcn_mfma_f32_16x16x16f16(vv[3][mi], pf[mi], O3, 0, 0, 0);
        }
        __builtin_amdgcn_s_setprio(0);

        if (c < 3) WRITEC(cur ^ 1);   // ds-write next chunk (waits its loads)
        __syncthreads();
    }

    int u = ((g * 32 + nt4 * 4 + w) << 3) + s;
    size_t ob = (size_t)(u * 16 + t) * 64;
    f16x4 ph;
#define PK(O) { ph[0]=(_Float16)O[0]; ph[1]=(_Float16)O[1]; ph[2]=(_Float16)O[2]; ph[3]=(_Float16)O[3]; }
    PK(O0) *(f16x4*)(Opart + ob + q*4)      = ph;
    PK(O1) *(f16x4*)(Opart + ob + 16 + q*4) = ph;
    PK(O2) *(f16x4*)(Opart + ob + 32 + q*4) = ph;
    PK(O3) *(f16x4*)(Opart + ob + 48 + q*4) = ph;
#undef PK
    if (q == 0) { Mpart[u*16 + t] = mrow; Lpart[u*16 + t] = lsum; }
#undef LOADC
#undef WRITEC
}

// ---------------- combine 8 split-M partials, normalize, + Wv_b ----------------
__global__ __launch_bounds__(256) void mega_combine(
    const _Float16* __restrict__ Opart, const float* __restrict__ Mpart,
    const float* __restrict__ Lpart, const float* __restrict__ Wv_b,
    float* __restrict__ outp)
{
    int idx = blockIdx.x * 256 + threadIdx.x;
    int n = idx >> 10, col = idx & 1023;
    int g = col >> 6, d = col & 63;
    int nt = n >> 4, t = n & 15;
    int u0 = ((g * 32 + nt) << 3);
    float ms[8];
    #pragma unroll
    for (int s = 0; s < 8; ++s) ms[s] = Mpart[(u0 + s) * 16 + t];
    float M = ms[0];
    #pragma unroll
    for (int s = 1; s < 8; ++s) M = fmaxf(M, ms[s]);
    float accO = 0.f, accL = 0.f;
    #pragma unroll
    for (int s = 0; s < 8; ++s) {
        float wgt = __builtin_exp2f(ms[s] - M);
        accO += wgt * (float)Opart[(size_t)((u0 + s) * 16 + t) * 64 + d];
        accL += wgt * Lpart[(u0 + s) * 16 + t];
    }
    outp[idx] = accO / accL + Wv_b[col];
}

extern "C" void kernel_launch(void* const* d_in, const int* in_sizes, int n_in,
                              void* d_out, int out_size, void* d_ws, size_t ws_size,
                              hipStream_t stream)
{
    const float* bbox     = (const float*)d_in[0];
    const float* ref_bbox = (const float*)d_in[1];
    const float* roi_feat = (const float*)d_in[2];
    const float* ref_feat = (const float*)d_in[3];
    const float* Wg_w = (const float*)d_in[4];
    const float* Wg_b = (const float*)d_in[5];
    const float* Wq_w = (const float*)d_in[6];
    const float* Wq_b = (const float*)d_in[7];
    const float* Wk_w = (const float*)d_in[8];
    const float* Wk_b = (const float*)d_in[9];
    const float* Wv_w = (const float*)d_in[10];
    const float* Wv_b = (const float*)d_in[11];
    const float* uvec = (const float*)d_in[12];
    float* outp = (float*)d_out;
    char* ws = (char*)d_ws;

    // prior [16][512][2048] f16 occupies [0,32M) and overlays the f16 input copies,
    // which are dead after the gemm role of mega_gp completes (prior blocks write
    // only to prior, which does not overlap roi_h/ref_h... NOTE: prior DOES overlap
    // them, but every gemm block finishes reading its A/B inputs before any data it
    // needs is overwritten only if prior blocks run after. To be safe, prior is
    // placed in the second 32 MB: no overlay.
    _Float16* roi_h = (_Float16*)(ws + 0);
    _Float16* ref_h = (_Float16*)(ws + (1ull<<20));
    _Float16* wq_h  = (_Float16*)(ws + (5ull<<20));
    _Float16* wk_h  = (_Float16*)(ws + (7ull<<20));
    _Float16* wv_h  = (_Float16*)(ws + (9ull<<20));
    _Float16* wg_h  = (_Float16*)(ws + (11ull<<20));
    size_t b2 = 12ull<<20;
    _Float16* prior = (_Float16*)(ws + b2);                    // 32 MB
    size_t b3 = b2 + (32ull<<20);
    _Float16* Qh    = (_Float16*)(ws + b3);
    _Float16* Kh    = (_Float16*)(ws + b3 + (1ull<<20));
    _Float16* Vth   = (_Float16*)(ws + b3 + (5ull<<20));
    _Float16* Opart = (_Float16*)(ws + b3 + (9ull<<20));
    float* Mpart    = (float*)(ws + b3 + (25ull<<20));
    float* Lpart    = (float*)(ws + b3 + (25ull<<20) + 262144);

    mega_prep<<<5633, 256, 0, stream>>>(roi_feat, ref_feat,
        Wg_w, Wq_w, Wk_w, Wv_w,
        roi_h, ref_h, wq_h, wk_h, wv_h, wg_h);
    mega_gp<<<2176, 256, 0, stream>>>(roi_h, ref_h, wq_h, wk_h, wv_h, wg_h,
        Wq_b, uvec, Wk_b, Wg_b, bbox, ref_bbox,
        Qh, Kh, Vth, prior);
    mega_attn<<<1024, 256, 0, stream>>>(Qh, Kh, Vth, prior, Opart, Mpart, Lpart);
    mega_combine<<<2048, 256, 0, stream>>>(Opart, Mpart, Lpart, Wv_b, outp);
}